// Round 1
// baseline (196.823 us; speedup 1.0000x reference)
//
#include <hip/hip_runtime.h>

#define N_PTS 20000
#define NCLS 20
#define KNN 16
#define GRID 12
#define NCELLS (GRID * GRID * GRID)
#define HCELL (1.0f / (float)GRID)
#define CAND_CAP 640       // worst staged block: bd>=2 hs=2 clipped 5^3 E~521 +5sig
#define KEY_CAP 128        // filtered keys per point (E~26; taumax corner E~48, edge E~96)
#define R_TARGET 0.0680f   // radius giving E[cnt]~26 in the interior

__device__ __forceinline__ int cell1d(float v) {
    int c = (int)(v * (float)GRID);
    return min(max(c, 0), GRID - 1);
}

// ---------------------------------------------------------------------------
// Device-scope grid barrier for co-resident grids. Caller guarantees all
// blocks resident (grid <= 2 blocks/CU worth of resources). Distinct counter
// per use (zeroed by the launch-front memset), so no sense-reversal needed.
// __threadfence() on gfx950 emits buffer_wbl2/buffer_inv sc1 -> cross-XCD
// L2 writeback/invalidate (per-XCD L2s are not coherent).
// ---------------------------------------------------------------------------
__device__ __forceinline__ void gridBarrier(int* bar, int nb) {
    __syncthreads();                 // drains vmcnt -> this block's stores at L2
    if (threadIdx.x == 0) {
        __threadfence();             // flush this XCD's L2 (release)
        atomicAdd(bar, 1);           // device-scope arrive
        while (__hip_atomic_load(bar, __ATOMIC_RELAXED, __HIP_MEMORY_SCOPE_AGENT) < nb)
            __builtin_amdgcn_s_sleep(2);
        __threadfence();             // invalidate caches (acquire)
    }
    __syncthreads();
}

// ---------------------------------------------------------------------------
// FUSED: count (grid atomics) + last-block 1728-cell scan + release-flag
// handshake + scatter (counting sort) + gather logits + softmax -> q0s, ls.
// 79 blocks <= 256 CUs: all blocks trivially co-resident, spin is safe.
// ---------------------------------------------------------------------------
__global__ __launch_bounds__(256) void build_kernel(const float* __restrict__ coords,
                                                    const float* __restrict__ logits,
                                                    int* __restrict__ cellCount,
                                                    int* __restrict__ doneCtr,
                                                    int* __restrict__ readyFlag,
                                                    int* __restrict__ cellStart,
                                                    int* __restrict__ cellCursor,
                                                    float4* __restrict__ sortedPts,
                                                    int* __restrict__ orig,
                                                    float* __restrict__ ls,
                                                    float* __restrict__ q0s) {
    const int p = blockIdx.x * blockDim.x + threadIdx.x;
    const bool act = (p < N_PTS);
    float x = 0.f, y = 0.f, z = 0.f;
    int c = 0;
    if (act) {
        x = coords[3 * p + 0];
        y = coords[3 * p + 1];
        z = coords[3 * p + 2];
        c = (cell1d(z) * GRID + cell1d(y)) * GRID + cell1d(x);
        atomicAdd(&cellCount[c], 1);
    }
    __threadfence();
    __syncthreads();
    __shared__ bool isLast;
    if (threadIdx.x == 0)
        isLast = (atomicAdd(doneCtr, 1) == (int)gridDim.x - 1);
    __syncthreads();

    if (isLast) {
        __shared__ int part[256];
        const int t = threadIdx.x;
        const int base = t * 7;                   // 256*7 = 1792 >= 1728
        int local[7];
        int s = 0;
#pragma unroll
        for (int i = 0; i < 7; ++i) {
            const int cc = base + i;
            const int v = (cc < NCELLS)
                ? __hip_atomic_load(&cellCount[cc], __ATOMIC_RELAXED, __HIP_MEMORY_SCOPE_AGENT)
                : 0;
            local[i] = s;
            s += v;
        }
        part[t] = s;
        __syncthreads();
        for (int off2 = 1; off2 < 256; off2 <<= 1) {
            const int v = part[t] + ((t >= off2) ? part[t - off2] : 0);
            __syncthreads();
            part[t] = v;
            __syncthreads();
        }
        const int excl = (t > 0) ? part[t - 1] : 0;
#pragma unroll
        for (int i = 0; i < 7; ++i) {
            const int cc = base + i;
            if (cc < NCELLS) {
                cellStart[cc] = excl + local[i];
                cellCursor[cc] = excl + local[i];
            }
        }
        if (t == 255) cellStart[NCELLS] = part[255];
        __syncthreads();                      // scan stores drained to L2
        if (t == 0) {
            __threadfence();                  // flush scan results device-wide
            __hip_atomic_store(readyFlag, 1, __ATOMIC_RELEASE, __HIP_MEMORY_SCOPE_AGENT);
        }
    }
    // all blocks wait for the scan to be published
    if (threadIdx.x == 0) {
        while (__hip_atomic_load(readyFlag, __ATOMIC_RELAXED, __HIP_MEMORY_SCOPE_AGENT) == 0)
            __builtin_amdgcn_s_sleep(2);
        __threadfence();
    }
    __syncthreads();
    if (!act) return;

    // ---- scatter phase (coords/cell already in registers) ----
    const int pos = atomicAdd(&cellCursor[c], 1);
    sortedPts[pos] = make_float4(x, y, z, __uint_as_float((unsigned)p));
    orig[pos] = p;
    const float4* l4 = (const float4*)(logits + p * NCLS);
    float v[NCLS];
#pragma unroll
    for (int u = 0; u < 5; ++u) {
        const float4 a = l4[u];
        v[4 * u + 0] = a.x; v[4 * u + 1] = a.y;
        v[4 * u + 2] = a.z; v[4 * u + 3] = a.w;
    }
    float4* d4 = (float4*)(ls + pos * NCLS);
#pragma unroll
    for (int u = 0; u < 5; ++u)
        d4[u] = make_float4(v[4 * u], v[4 * u + 1], v[4 * u + 2], v[4 * u + 3]);
    float mx = v[0];
#pragma unroll
    for (int cc2 = 1; cc2 < NCLS; ++cc2) mx = fmaxf(mx, v[cc2]);
    float sum = 0.f;
#pragma unroll
    for (int cc2 = 0; cc2 < NCLS; ++cc2) { v[cc2] = __expf(v[cc2] - mx); sum += v[cc2]; }
    const float inv = 1.f / sum;
    float4* q4 = (float4*)(q0s + pos * NCLS);
#pragma unroll
    for (int u = 0; u < 5; ++u)
        q4[u] = make_float4(v[4 * u] * inv, v[4 * u + 1] * inv,
                            v[4 * u + 2] * inv, v[4 * u + 3] * inv);
}

// ---------------------------------------------------------------------------
// Rare exact fallback: wave-cooperative global-memory ladder (hw growing).
// Only ~100-200 face-cell points (Poisson undercount) ever reach this.
// ---------------------------------------------------------------------------
__device__ void knn_ladder(const float4* __restrict__ sortedPts,
                           const int* __restrict__ cellStart,
                           const float4 qp, const int s, int hw,
                           unsigned long long* keys, const int lane,
                           int* __restrict__ knn_out) {
    const unsigned long long laneLt = (1ull << lane) - 1ull;
    const int cx = cell1d(qp.x), cy = cell1d(qp.y), cz = cell1d(qp.z);
    float g = 0.9995f * (float)hw * HCELL;
    float tau = g * g;
    int cnt = 0;
    for (int att = 0; att < 16; ++att) {
        cnt = 0;
        const int xlo = max(cx - hw, 0), xhi = min(cx + hw, GRID - 1);
        const int ylo = max(cy - hw, 0), yhi = min(cy + hw, GRID - 1);
        const int zlo = max(cz - hw, 0), zhi = min(cz + hw, GRID - 1);
        for (int zz = zlo; zz <= zhi; ++zz) {
            for (int yy = ylo; yy <= yhi; ++yy) {
                const int rowc = (zz * GRID + yy) * GRID;
                const int beg = cellStart[rowc + xlo];
                const int end = cellStart[rowc + xhi + 1];
                for (int j0 = beg; j0 < end; j0 += 64) {
                    const int j = j0 + lane;
                    const bool jv = j < end;
                    const float4 pt = sortedPts[jv ? j : beg];
                    const float dx = pt.x - qp.x, dy = pt.y - qp.y, dz = pt.z - qp.z;
                    const float d2 = dx * dx + dy * dy + dz * dz;
                    const bool take = jv && (d2 < tau);
                    const unsigned long long mm = __ballot(take);
                    if (take) {
                        const int pos = cnt + (int)__popcll(mm & laneLt);
                        if (pos < KEY_CAP)
                            keys[pos] = (((unsigned long long)__float_as_uint(d2)) << 32) |
                                        (unsigned long long)(unsigned)j;
                    }
                    cnt += (int)__popcll(mm);
                }
            }
        }
        if (cnt >= KNN && cnt <= KEY_CAP) break;
        if (cnt < KNN) {
            if (hw < GRID - 1) { ++hw; g = 0.9995f * (float)hw * HCELL; tau = g * g; }
            else tau *= 2.5f;
        } else {
            tau *= 0.6f;
        }
    }
    const int m = min(cnt, KEY_CAP);
    const unsigned long long k0 = (lane < m) ? keys[lane] : ~0ull;
    const unsigned long long k1 = (lane + 64 < m) ? keys[lane + 64] : ~0ull;
    int r0 = 0, r1 = 0;
    for (int j = 0; j < m; ++j) {
        const unsigned long long kj = keys[j];
        r0 += (kj < k0); r1 += (kj < k1);
    }
    if (lane < m && r0 < KNN)      knn_out[s * KNN + r0] = (int)(unsigned)(k0 & 0xffffffffull);
    if (lane + 64 < m && r1 < KNN) knn_out[s * KNN + r1] = (int)(unsigned)(k1 & 0xffffffffull);
}

// ---------------------------------------------------------------------------
// kNN: TWO blocks per cell (3456 blocks, 14.3KB LDS -> 8 blocks/CU).
// (unchanged this round)
// ---------------------------------------------------------------------------
__global__ __launch_bounds__(256) void knn_kernel(const float4* __restrict__ sortedPts,
                                                  const int* __restrict__ cellStart,
                                                  int* __restrict__ knn_out) {
    __shared__ float4 cand[CAND_CAP];                 // 10.24 KB
    __shared__ unsigned long long keys[4][KEY_CAP];   // 4 KB
    const int lane = threadIdx.x & 63;
    const int wave = threadIdx.x >> 6;
    const int c = blockIdx.x >> 1;
    const int half = blockIdx.x & 1;
    const int cz = c / (GRID * GRID);
    const int cy = (c / GRID) % GRID;
    const int cx = c % GRID;
    const int pbeg = cellStart[c];
    const int pend = cellStart[c + 1];
    const int npts = pend - pbeg;
    if (npts <= 0) return;
    const int bd = (cx == 0 || cx == GRID - 1) + (cy == 0 || cy == GRID - 1) +
                   (cz == 0 || cz == GRID - 1);
    const int hs = (bd >= 2) ? 2 : 1;                 // staging halo width
    const unsigned long long laneLt = (1ull << lane) - 1ull;

    const int xlo = max(cx - hs, 0), xhi = min(cx + hs, GRID - 1);
    const int ylo = max(cy - hs, 0), yhi = min(cy + hs, GRID - 1);
    const int zlo = max(cz - hs, 0), zhi = min(cz + hs, GRID - 1);
    const int ny = yhi - ylo + 1;
    const int nruns = (zhi - zlo + 1) * ny;           // <= 25 x-contiguous runs

    int beg = 0, len = 0;
    if (lane < nruns) {
        const int zz = zlo + lane / ny;
        const int yy = ylo + lane % ny;
        const int rowc = (zz * GRID + yy) * GRID;
        beg = cellStart[rowc + xlo];
        len = cellStart[rowc + xhi + 1] - beg;
    }
    int off = len;
#pragma unroll
    for (int sh = 1; sh < 32; sh <<= 1) {
        const int o = __shfl_up(off, sh, 64);
        if (lane >= sh) off += o;
    }
    const int nc = __shfl(off, nruns - 1);
    off -= len;                                        // exclusive
    const int ownRun = (cz - zlo) * ny + (cy - ylo);
    const int ownOff = __shfl(off, ownRun) + (pbeg - __shfl(beg, ownRun));

    if (nc <= CAND_CAP) {
        for (int r = wave; r < nruns; r += 4) {
            const int rb = __shfl(beg, r);
            const int rl = __shfl(len, r);
            const int ro = __shfl(off, r);
            for (int i = lane; i < rl; i += 64) {
                float4 pt = sortedPts[rb + i];
                pt.w = __uint_as_float((unsigned)(rb + i));
                cand[ro + i] = pt;
            }
        }
    }
    __syncthreads();

    if (nc > CAND_CAP) {                               // ~never (>5 sigma)
        for (int idx = 2 * wave + half; idx < npts; idx += 8)
            knn_ladder(sortedPts, cellStart, sortedPts[pbeg + idx], pbeg + idx,
                       hs, keys[wave], lane, knn_out);
        return;
    }

    const float taumaxr = 0.9995f * (float)hs * HCELL;
    const float taumax = taumaxr * taumaxr;

    for (int idx = 2 * wave + half; idx < npts; idx += 8) {
        const int s = pbeg + idx;
        const float4 qp = cand[ownOff + idx];
        // boundary-corrected tau targeting E[cnt]~26, capped at coverage hs*h
        float r = R_TARGET;
        const float inv2r = 0.5f / r;
        const float fx = (fminf(qp.x + r, 1.f) - fmaxf(qp.x - r, 0.f)) * inv2r;
        const float fy = (fminf(qp.y + r, 1.f) - fmaxf(qp.y - r, 0.f)) * inv2r;
        const float fz = (fminf(qp.z + r, 1.f) - fmaxf(qp.z - r, 0.f)) * inv2r;
        const float f = fmaxf(fx * fy * fz, 0.05f);
        r = R_TARGET * __powf(f, -0.33333334f);
        float tau = fminf(r * r, taumax);
        bool triedMax = (tau >= taumax * 0.999f);

        int cnt = 0;
        bool ok = false;
        for (int att = 0; att < 5 && !ok; ++att) {
            cnt = 0;
            for (int j0 = 0; j0 < nc; j0 += 64) {
                const int j = j0 + lane;
                float d2 = 1e30f;
                unsigned pw = 0;
                if (j < nc) {
                    const float4 pt = cand[j];
                    const float dx = pt.x - qp.x, dy = pt.y - qp.y, dz = pt.z - qp.z;
                    d2 = dx * dx + dy * dy + dz * dz;
                    pw = __float_as_uint(pt.w);
                }
                const bool take = d2 < tau;
                const unsigned long long mm = __ballot(take);
                if (take) {
                    const int pos = cnt + (int)__popcll(mm & laneLt);
                    if (pos < KEY_CAP)
                        keys[wave][pos] =
                            (((unsigned long long)__float_as_uint(d2)) << 32) |
                            (unsigned long long)pw;
                }
                cnt += (int)__popcll(mm);
            }
            if (cnt >= KNN && cnt <= KEY_CAP) ok = true;
            else if (cnt < KNN) {
                if (triedMax) break;                   // needs radius > hs*h -> ladder
                tau = taumax; triedMax = true;
            } else tau *= 0.6f;
        }
        if (!ok) {                                     // rare Poisson-tail points
            knn_ladder(sortedPts, cellStart, qp, s, hs + 1, keys[wave], lane, knn_out);
            continue;
        }
        const int m = cnt;
        const unsigned long long k0 = (lane < m) ? keys[wave][lane] : ~0ull;
        const unsigned long long k1 = (lane + 64 < m) ? keys[wave][lane + 64] : ~0ull;
        int r0 = 0, r1 = 0;
        for (int j = 0; j < m; ++j) {
            const unsigned long long kj = keys[wave][j];   // LDS broadcast
            r0 += (kj < k0); r1 += (kj < k1);
        }
        if (lane < m && r0 < KNN)      knn_out[s * KNN + r0] = (int)(unsigned)(k0 & 0xffffffffull);
        if (lane + 64 < m && r1 < KNN) knn_out[s * KNN + r1] = (int)(unsigned)(k1 & 0xffffffffull);
    }
}

// ---------------------------------------------------------------------------
// FUSED: all 3 CRF iterations in one kernel, SORTED space, 4 lanes/point.
// 313 blocks x 256 thr, 1.6KB LDS -> >=2 blocks/CU guaranteed co-resident;
// device-scope grid barriers between iterations. knn indices + ls row are
// loaded ONCE into registers and reused across all 3 iterations.
// NOTE: q0s/q1s/outQ intentionally NOT __restrict__ (outQ aliases q1s).
// ---------------------------------------------------------------------------
__global__ __launch_bounds__(256) void crf3_kernel(const float* __restrict__ ls,
                                                   const float* __restrict__ W,
                                                   const int* __restrict__ knn,
                                                   float* q0s, float* q1s,
                                                   const int* __restrict__ orig,
                                                   float* outRef, float* outQ,
                                                   int* bar) {
    __shared__ float Ws[NCLS * NCLS];
    for (int i = threadIdx.x; i < NCLS * NCLS; i += blockDim.x) Ws[i] = W[i];
    const int t = blockIdx.x * blockDim.x + threadIdx.x;
    const int p = t >> 2;
    const int qtr = t & 3;
    const bool act = (p < N_PTS);
    const int c0 = qtr * 5;

    int4 k4 = make_int4(0, 0, 0, 0);
    float lsr[5] = {0.f, 0.f, 0.f, 0.f, 0.f};
    if (act) {
        k4 = ((const int4*)(knn + p * KNN))[qtr];
#pragma unroll
        for (int i = 0; i < 5; ++i) lsr[i] = ls[p * NCLS + c0 + i];
    }
    __syncthreads();                                   // Ws ready

    const float* qin = q0s;
    for (int it = 0; it < 3; ++it) {
        if (act) {
            float acc[NCLS];
#pragma unroll
            for (int c = 0; c < NCLS; ++c) acc[c] = 0.f;
            const int ids[4] = {k4.x, k4.y, k4.z, k4.w};
#pragma unroll
            for (int u = 0; u < 4; ++u) {
                unsigned id = (unsigned)ids[u];
                if (id >= N_PTS) id = 0;               // safety clamp (unreachable)
                const float4* r4 = (const float4*)(qin + id * NCLS);
#pragma unroll
                for (int v = 0; v < 5; ++v) {
                    const float4 a = r4[v];
                    acc[4 * v + 0] += a.x; acc[4 * v + 1] += a.y;
                    acc[4 * v + 2] += a.z; acc[4 * v + 3] += a.w;
                }
            }
#pragma unroll
            for (int c = 0; c < NCLS; ++c) {
                acc[c] += __shfl_xor(acc[c], 1, 64);
                acc[c] += __shfl_xor(acc[c], 2, 64);
                acc[c] *= (1.f / 16.f);                // msg
            }
            float ref[5];
#pragma unroll
            for (int i = 0; i < 5; ++i) {
                float s = lsr[i];
#pragma unroll
                for (int k = 0; k < NCLS; ++k) s += acc[k] * Ws[(c0 + i) * NCLS + k];  // x@W^T
                ref[i] = s;
            }
            float mx = ref[0];
#pragma unroll
            for (int i = 1; i < 5; ++i) mx = fmaxf(mx, ref[i]);
            mx = fmaxf(mx, __shfl_xor(mx, 1, 64));
            mx = fmaxf(mx, __shfl_xor(mx, 2, 64));
            float ex[5];
            float ps = 0.f;
#pragma unroll
            for (int i = 0; i < 5; ++i) { ex[i] = __expf(ref[i] - mx); ps += ex[i]; }
            ps += __shfl_xor(ps, 1, 64);
            ps += __shfl_xor(ps, 2, 64);
            const float inv = 1.f / ps;

            if (it == 2) {
                const int o = orig[p];
#pragma unroll
                for (int i = 0; i < 5; ++i) {
                    outRef[o * NCLS + c0 + i] = ref[i];
                    outQ[o * NCLS + c0 + i] = ex[i] * inv;
                }
            } else {
                float* qout = (it == 0) ? q1s : q0s;
#pragma unroll
                for (int i = 0; i < 5; ++i) qout[p * NCLS + c0 + i] = ex[i] * inv;
            }
        }
        if (it == 0)      { gridBarrier(bar + 0, (int)gridDim.x); qin = q1s; }
        else if (it == 1) { gridBarrier(bar + 1, (int)gridDim.x); qin = q0s; }
    }
}

// ---------------------------------------------------------------------------
extern "C" void kernel_launch(void* const* d_in, const int* in_sizes, int n_in,
                              void* d_out, int out_size, void* d_ws, size_t ws_size,
                              hipStream_t stream) {
    const float* logits = (const float*)d_in[0];   // (20000, 20)
    const float* coords = (const float*)d_in[1];   // (20000, 3)
    const float* W      = (const float*)d_in[2];   // (20, 20)
    float* out = (float*)d_out;                    // refined (400000) | q (400000)

    // workspace (~5 MB); q1s aliases out's q-region (safe: final pass reads
    // only q0s/ls/knn/orig and overwrites that region last).
    char* ws = (char*)d_ws;
    size_t off = 0;
    int* knn = (int*)(ws + off);              off += (size_t)N_PTS * KNN * 4;
    off = (off + 255) & ~(size_t)255;
    float* ls = (float*)(ws + off);           off += (size_t)N_PTS * NCLS * 4;
    off = (off + 255) & ~(size_t)255;
    float* q0s = (float*)(ws + off);          off += (size_t)N_PTS * NCLS * 4;
    off = (off + 255) & ~(size_t)255;
    float4* sortedPts = (float4*)(ws + off);  off += (size_t)N_PTS * 16;
    off = (off + 255) & ~(size_t)255;
    int* orig = (int*)(ws + off);             off += (size_t)N_PTS * 4;
    off = (off + 255) & ~(size_t)255;
    int* cellCount = (int*)(ws + off);        off += (size_t)(NCELLS + 4) * 4;
    int* doneCtr   = cellCount + NCELLS;      // zeroed with cellCount
    int* readyFlag = cellCount + NCELLS + 1;
    int* bar       = cellCount + NCELLS + 2;  // 2 counters
    off = (off + 255) & ~(size_t)255;
    int* cellStart = (int*)(ws + off);        off += (size_t)(NCELLS + 1) * 4;
    off = (off + 255) & ~(size_t)255;
    int* cellCursor = (int*)(ws + off);
    float* q1s = out + N_PTS * NCLS;

    const int threads = 256;
    const int pblocks = (N_PTS + threads - 1) / threads;      // 79
    const int cblocks = (4 * N_PTS + threads - 1) / threads;  // 313

    hipMemsetAsync(cellCount, 0, (NCELLS + 4) * sizeof(int), stream);
    build_kernel<<<pblocks, threads, 0, stream>>>(coords, logits, cellCount, doneCtr,
                                                  readyFlag, cellStart, cellCursor,
                                                  sortedPts, orig, ls, q0s);
    knn_kernel<<<NCELLS * 2, threads, 0, stream>>>(sortedPts, cellStart, knn);
    crf3_kernel<<<cblocks, threads, 0, stream>>>(ls, W, knn, q0s, q1s, orig,
                                                 out, out + N_PTS * NCLS, bar);
}

// Round 2
// 193.722 us; speedup vs baseline: 1.0160x; 1.0160x over previous
//
#include <hip/hip_runtime.h>

#define N_PTS 20000
#define NCLS 20
#define KNN 16
#define GRID 12
#define NCELLS (GRID * GRID * GRID)
#define HCELL (1.0f / (float)GRID)
#define CAND_CAP 640       // worst staged block: bd>=2 hs=2 clipped 5^3 E~521 +5sig
#define KEY_CAP 128        // filtered keys per point (E~26; taumax corner E~48, edge E~96)
#define R_TARGET 0.0680f   // radius giving E[cnt]~26 in the interior

__device__ __forceinline__ int cell1d(float v) {
    int c = (int)(v * (float)GRID);
    return min(max(c, 0), GRID - 1);
}

// ---------------------------------------------------------------------------
// Fence-free device-scope grid barrier. Correctness contract: ALL cross-block
// data published before the barrier is written with agent-scope coherent
// stores (sc1, completes at L3 coherence point), and ALL cross-block reads
// after the barrier use agent-scope coherent loads (bypass stale L1/L2).
// Then no buffer_wbl2/buffer_inv (full L2 writeback/invalidate -- the 30us/
// barrier cost observed in round 1) is needed: __syncthreads() drains vmcnt,
// so every sc1 store is globally ordered before the relaxed arrive RMW.
// ---------------------------------------------------------------------------
__device__ __forceinline__ void gridBarrier(int* bar, int nb) {
    __syncthreads();                 // s_waitcnt vmcnt(0): sc1 stores at L3
    if (threadIdx.x == 0) {
        __hip_atomic_fetch_add(bar, 1, __ATOMIC_RELAXED, __HIP_MEMORY_SCOPE_AGENT);
        while (__hip_atomic_load(bar, __ATOMIC_RELAXED, __HIP_MEMORY_SCOPE_AGENT) < nb)
            __builtin_amdgcn_s_sleep(2);
    }
    __syncthreads();
}

// ---------------------------------------------------------------------------
// FUSED: count (grid atomics) + last-block 1728-cell scan + release-flag
// handshake + scatter (counting sort) + gather logits + softmax -> q0s, ls.
// 79 blocks <= 256 CUs: all blocks trivially co-resident, spin is safe.
// Fence-free: counts/cursor are coherent RMWs; cellCursor init + readyFlag
// are sc1 stores; consumers of cellCursor are coherent RMWs.
// ---------------------------------------------------------------------------
__global__ __launch_bounds__(256) void build_kernel(const float* __restrict__ coords,
                                                    const float* __restrict__ logits,
                                                    int* __restrict__ cellCount,
                                                    int* __restrict__ doneCtr,
                                                    int* __restrict__ readyFlag,
                                                    int* __restrict__ cellStart,
                                                    int* __restrict__ cellCursor,
                                                    float4* __restrict__ sortedPts,
                                                    int* __restrict__ orig,
                                                    float* __restrict__ ls,
                                                    float* __restrict__ q0s) {
    const int p = blockIdx.x * blockDim.x + threadIdx.x;
    const bool act = (p < N_PTS);
    float x = 0.f, y = 0.f, z = 0.f;
    int c = 0;
    if (act) {
        x = coords[3 * p + 0];
        y = coords[3 * p + 1];
        z = coords[3 * p + 2];
        c = (cell1d(z) * GRID + cell1d(y)) * GRID + cell1d(x);
        atomicAdd(&cellCount[c], 1);      // coherent RMW (device scope)
    }
    __syncthreads();                      // drains vmcnt: RMWs globally ordered
    __shared__ bool isLast;
    if (threadIdx.x == 0)
        isLast = (atomicAdd(doneCtr, 1) == (int)gridDim.x - 1);
    __syncthreads();

    if (isLast) {
        __shared__ int part[256];
        const int t = threadIdx.x;
        const int base = t * 7;                   // 256*7 = 1792 >= 1728
        int local[7];
        int s = 0;
#pragma unroll
        for (int i = 0; i < 7; ++i) {
            const int cc = base + i;
            const int v = (cc < NCELLS)
                ? __hip_atomic_load(&cellCount[cc], __ATOMIC_RELAXED, __HIP_MEMORY_SCOPE_AGENT)
                : 0;
            local[i] = s;
            s += v;
        }
        part[t] = s;
        __syncthreads();
        for (int off2 = 1; off2 < 256; off2 <<= 1) {
            const int v = part[t] + ((t >= off2) ? part[t - off2] : 0);
            __syncthreads();
            part[t] = v;
            __syncthreads();
        }
        const int excl = (t > 0) ? part[t - 1] : 0;
#pragma unroll
        for (int i = 0; i < 7; ++i) {
            const int cc = base + i;
            if (cc < NCELLS) {
                // cellStart: consumed by NEXT kernel (end-of-kernel flush) ->
                // regular store. cellCursor: consumed by coherent RMWs in THIS
                // kernel -> sc1 store.
                cellStart[cc] = excl + local[i];
                __hip_atomic_store(&cellCursor[cc], excl + local[i],
                                   __ATOMIC_RELAXED, __HIP_MEMORY_SCOPE_AGENT);
            }
        }
        if (t == 255) cellStart[NCELLS] = part[255];
        __syncthreads();                      // all sc1 cursor stores at L3
        if (t == 0)
            __hip_atomic_store(readyFlag, 1, __ATOMIC_RELAXED, __HIP_MEMORY_SCOPE_AGENT);
    }
    // all blocks wait for the scan to be published
    if (threadIdx.x == 0) {
        while (__hip_atomic_load(readyFlag, __ATOMIC_RELAXED, __HIP_MEMORY_SCOPE_AGENT) == 0)
            __builtin_amdgcn_s_sleep(2);
    }
    __syncthreads();
    if (!act) return;

    // ---- scatter phase (coords/cell already in registers) ----
    const int pos = atomicAdd(&cellCursor[c], 1);   // coherent RMW: sees sc1 init
    sortedPts[pos] = make_float4(x, y, z, __uint_as_float((unsigned)p));
    orig[pos] = p;
    const float4* l4 = (const float4*)(logits + p * NCLS);
    float v[NCLS];
#pragma unroll
    for (int u = 0; u < 5; ++u) {
        const float4 a = l4[u];
        v[4 * u + 0] = a.x; v[4 * u + 1] = a.y;
        v[4 * u + 2] = a.z; v[4 * u + 3] = a.w;
    }
    float4* d4 = (float4*)(ls + pos * NCLS);
#pragma unroll
    for (int u = 0; u < 5; ++u)
        d4[u] = make_float4(v[4 * u], v[4 * u + 1], v[4 * u + 2], v[4 * u + 3]);
    float mx = v[0];
#pragma unroll
    for (int cc2 = 1; cc2 < NCLS; ++cc2) mx = fmaxf(mx, v[cc2]);
    float sum = 0.f;
#pragma unroll
    for (int cc2 = 0; cc2 < NCLS; ++cc2) { v[cc2] = __expf(v[cc2] - mx); sum += v[cc2]; }
    const float inv = 1.f / sum;
    float4* q4 = (float4*)(q0s + pos * NCLS);
#pragma unroll
    for (int u = 0; u < 5; ++u)
        q4[u] = make_float4(v[4 * u] * inv, v[4 * u + 1] * inv,
                            v[4 * u + 2] * inv, v[4 * u + 3] * inv);
}

// ---------------------------------------------------------------------------
// Rare exact fallback: wave-cooperative global-memory ladder (hw growing).
// Only ~100-200 face-cell points (Poisson undercount) ever reach this.
// ---------------------------------------------------------------------------
__device__ void knn_ladder(const float4* __restrict__ sortedPts,
                           const int* __restrict__ cellStart,
                           const float4 qp, const int s, int hw,
                           unsigned long long* keys, const int lane,
                           int* __restrict__ knn_out) {
    const unsigned long long laneLt = (1ull << lane) - 1ull;
    const int cx = cell1d(qp.x), cy = cell1d(qp.y), cz = cell1d(qp.z);
    float g = 0.9995f * (float)hw * HCELL;
    float tau = g * g;
    int cnt = 0;
    for (int att = 0; att < 16; ++att) {
        cnt = 0;
        const int xlo = max(cx - hw, 0), xhi = min(cx + hw, GRID - 1);
        const int ylo = max(cy - hw, 0), yhi = min(cy + hw, GRID - 1);
        const int zlo = max(cz - hw, 0), zhi = min(cz + hw, GRID - 1);
        for (int zz = zlo; zz <= zhi; ++zz) {
            for (int yy = ylo; yy <= yhi; ++yy) {
                const int rowc = (zz * GRID + yy) * GRID;
                const int beg = cellStart[rowc + xlo];
                const int end = cellStart[rowc + xhi + 1];
                for (int j0 = beg; j0 < end; j0 += 64) {
                    const int j = j0 + lane;
                    const bool jv = j < end;
                    const float4 pt = sortedPts[jv ? j : beg];
                    const float dx = pt.x - qp.x, dy = pt.y - qp.y, dz = pt.z - qp.z;
                    const float d2 = dx * dx + dy * dy + dz * dz;
                    const bool take = jv && (d2 < tau);
                    const unsigned long long mm = __ballot(take);
                    if (take) {
                        const int pos = cnt + (int)__popcll(mm & laneLt);
                        if (pos < KEY_CAP)
                            keys[pos] = (((unsigned long long)__float_as_uint(d2)) << 32) |
                                        (unsigned long long)(unsigned)j;
                    }
                    cnt += (int)__popcll(mm);
                }
            }
        }
        if (cnt >= KNN && cnt <= KEY_CAP) break;
        if (cnt < KNN) {
            if (hw < GRID - 1) { ++hw; g = 0.9995f * (float)hw * HCELL; tau = g * g; }
            else tau *= 2.5f;
        } else {
            tau *= 0.6f;
        }
    }
    const int m = min(cnt, KEY_CAP);
    const unsigned long long k0 = (lane < m) ? keys[lane] : ~0ull;
    const unsigned long long k1 = (lane + 64 < m) ? keys[lane + 64] : ~0ull;
    int r0 = 0, r1 = 0;
    for (int j = 0; j < m; ++j) {
        const unsigned long long kj = keys[j];
        r0 += (kj < k0); r1 += (kj < k1);
    }
    if (lane < m && r0 < KNN)      knn_out[s * KNN + r0] = (int)(unsigned)(k0 & 0xffffffffull);
    if (lane + 64 < m && r1 < KNN) knn_out[s * KNN + r1] = (int)(unsigned)(k1 & 0xffffffffull);
}

// ---------------------------------------------------------------------------
// kNN: TWO blocks per cell (3456 blocks, 14.3KB LDS -> 8 blocks/CU).
// (unchanged this round)
// ---------------------------------------------------------------------------
__global__ __launch_bounds__(256) void knn_kernel(const float4* __restrict__ sortedPts,
                                                  const int* __restrict__ cellStart,
                                                  int* __restrict__ knn_out) {
    __shared__ float4 cand[CAND_CAP];                 // 10.24 KB
    __shared__ unsigned long long keys[4][KEY_CAP];   // 4 KB
    const int lane = threadIdx.x & 63;
    const int wave = threadIdx.x >> 6;
    const int c = blockIdx.x >> 1;
    const int half = blockIdx.x & 1;
    const int cz = c / (GRID * GRID);
    const int cy = (c / GRID) % GRID;
    const int cx = c % GRID;
    const int pbeg = cellStart[c];
    const int pend = cellStart[c + 1];
    const int npts = pend - pbeg;
    if (npts <= 0) return;
    const int bd = (cx == 0 || cx == GRID - 1) + (cy == 0 || cy == GRID - 1) +
                   (cz == 0 || cz == GRID - 1);
    const int hs = (bd >= 2) ? 2 : 1;                 // staging halo width
    const unsigned long long laneLt = (1ull << lane) - 1ull;

    const int xlo = max(cx - hs, 0), xhi = min(cx + hs, GRID - 1);
    const int ylo = max(cy - hs, 0), yhi = min(cy + hs, GRID - 1);
    const int zlo = max(cz - hs, 0), zhi = min(cz + hs, GRID - 1);
    const int ny = yhi - ylo + 1;
    const int nruns = (zhi - zlo + 1) * ny;           // <= 25 x-contiguous runs

    int beg = 0, len = 0;
    if (lane < nruns) {
        const int zz = zlo + lane / ny;
        const int yy = ylo + lane % ny;
        const int rowc = (zz * GRID + yy) * GRID;
        beg = cellStart[rowc + xlo];
        len = cellStart[rowc + xhi + 1] - beg;
    }
    int off = len;
#pragma unroll
    for (int sh = 1; sh < 32; sh <<= 1) {
        const int o = __shfl_up(off, sh, 64);
        if (lane >= sh) off += o;
    }
    const int nc = __shfl(off, nruns - 1);
    off -= len;                                        // exclusive
    const int ownRun = (cz - zlo) * ny + (cy - ylo);
    const int ownOff = __shfl(off, ownRun) + (pbeg - __shfl(beg, ownRun));

    if (nc <= CAND_CAP) {
        for (int r = wave; r < nruns; r += 4) {
            const int rb = __shfl(beg, r);
            const int rl = __shfl(len, r);
            const int ro = __shfl(off, r);
            for (int i = lane; i < rl; i += 64) {
                float4 pt = sortedPts[rb + i];
                pt.w = __uint_as_float((unsigned)(rb + i));
                cand[ro + i] = pt;
            }
        }
    }
    __syncthreads();

    if (nc > CAND_CAP) {                               // ~never (>5 sigma)
        for (int idx = 2 * wave + half; idx < npts; idx += 8)
            knn_ladder(sortedPts, cellStart, sortedPts[pbeg + idx], pbeg + idx,
                       hs, keys[wave], lane, knn_out);
        return;
    }

    const float taumaxr = 0.9995f * (float)hs * HCELL;
    const float taumax = taumaxr * taumaxr;

    for (int idx = 2 * wave + half; idx < npts; idx += 8) {
        const int s = pbeg + idx;
        const float4 qp = cand[ownOff + idx];
        // boundary-corrected tau targeting E[cnt]~26, capped at coverage hs*h
        float r = R_TARGET;
        const float inv2r = 0.5f / r;
        const float fx = (fminf(qp.x + r, 1.f) - fmaxf(qp.x - r, 0.f)) * inv2r;
        const float fy = (fminf(qp.y + r, 1.f) - fmaxf(qp.y - r, 0.f)) * inv2r;
        const float fz = (fminf(qp.z + r, 1.f) - fmaxf(qp.z - r, 0.f)) * inv2r;
        const float f = fmaxf(fx * fy * fz, 0.05f);
        r = R_TARGET * __powf(f, -0.33333334f);
        float tau = fminf(r * r, taumax);
        bool triedMax = (tau >= taumax * 0.999f);

        int cnt = 0;
        bool ok = false;
        for (int att = 0; att < 5 && !ok; ++att) {
            cnt = 0;
            for (int j0 = 0; j0 < nc; j0 += 64) {
                const int j = j0 + lane;
                float d2 = 1e30f;
                unsigned pw = 0;
                if (j < nc) {
                    const float4 pt = cand[j];
                    const float dx = pt.x - qp.x, dy = pt.y - qp.y, dz = pt.z - qp.z;
                    d2 = dx * dx + dy * dy + dz * dz;
                    pw = __float_as_uint(pt.w);
                }
                const bool take = d2 < tau;
                const unsigned long long mm = __ballot(take);
                if (take) {
                    const int pos = cnt + (int)__popcll(mm & laneLt);
                    if (pos < KEY_CAP)
                        keys[wave][pos] =
                            (((unsigned long long)__float_as_uint(d2)) << 32) |
                            (unsigned long long)pw;
                }
                cnt += (int)__popcll(mm);
            }
            if (cnt >= KNN && cnt <= KEY_CAP) ok = true;
            else if (cnt < KNN) {
                if (triedMax) break;                   // needs radius > hs*h -> ladder
                tau = taumax; triedMax = true;
            } else tau *= 0.6f;
        }
        if (!ok) {                                     // rare Poisson-tail points
            knn_ladder(sortedPts, cellStart, qp, s, hs + 1, keys[wave], lane, knn_out);
            continue;
        }
        const int m = cnt;
        const unsigned long long k0 = (lane < m) ? keys[wave][lane] : ~0ull;
        const unsigned long long k1 = (lane + 64 < m) ? keys[wave][lane + 64] : ~0ull;
        int r0 = 0, r1 = 0;
        for (int j = 0; j < m; ++j) {
            const unsigned long long kj = keys[wave][j];   // LDS broadcast
            r0 += (kj < k0); r1 += (kj < k1);
        }
        if (lane < m && r0 < KNN)      knn_out[s * KNN + r0] = (int)(unsigned)(k0 & 0xffffffffull);
        if (lane + 64 < m && r1 < KNN) knn_out[s * KNN + r1] = (int)(unsigned)(k1 & 0xffffffffull);
    }
}

// ---------------------------------------------------------------------------
// FUSED: all 3 CRF iterations in one kernel, SORTED space, 4 lanes/point.
// 313 blocks x 256 thr -> all co-resident. Fence-free barriers: every q
// store between barriers is an agent-scope sc1 store, every q gather load
// is an agent-scope sc1 load (8B), so NO L2 writeback/invalidate is needed.
// knn indices + ls row loaded ONCE into registers across all 3 iterations.
// NOTE: q0s/q1s/outQ intentionally NOT __restrict__ (outQ aliases q1s).
// ---------------------------------------------------------------------------
__global__ __launch_bounds__(256) void crf3_kernel(const float* __restrict__ ls,
                                                   const float* __restrict__ W,
                                                   const int* __restrict__ knn,
                                                   float* q0s, float* q1s,
                                                   const int* __restrict__ orig,
                                                   float* outRef, float* outQ,
                                                   int* bar) {
    __shared__ float Ws[NCLS * NCLS];
    for (int i = threadIdx.x; i < NCLS * NCLS; i += blockDim.x) Ws[i] = W[i];
    const int t = blockIdx.x * blockDim.x + threadIdx.x;
    const int p = t >> 2;
    const int qtr = t & 3;
    const bool act = (p < N_PTS);
    const int c0 = qtr * 5;

    int4 k4 = make_int4(0, 0, 0, 0);
    float lsr[5] = {0.f, 0.f, 0.f, 0.f, 0.f};
    if (act) {
        k4 = ((const int4*)(knn + p * KNN))[qtr];
#pragma unroll
        for (int i = 0; i < 5; ++i) lsr[i] = ls[p * NCLS + c0 + i];
    }
    __syncthreads();                                   // Ws ready

    const float* qin = q0s;
    for (int it = 0; it < 3; ++it) {
        if (act) {
            float acc[NCLS];
#pragma unroll
            for (int c = 0; c < NCLS; ++c) acc[c] = 0.f;
            const int ids[4] = {k4.x, k4.y, k4.z, k4.w};
#pragma unroll
            for (int u = 0; u < 4; ++u) {
                unsigned id = (unsigned)ids[u];
                if (id >= N_PTS) id = 0;               // safety clamp (unreachable)
                // coherent 8B gather: bypasses (possibly stale) L1/L2, reads L3
                const unsigned long long* r8 =
                    (const unsigned long long*)(qin + id * NCLS);
#pragma unroll
                for (int v = 0; v < 10; ++v) {
                    const unsigned long long uu = __hip_atomic_load(
                        r8 + v, __ATOMIC_RELAXED, __HIP_MEMORY_SCOPE_AGENT);
                    acc[2 * v + 0] += __uint_as_float((unsigned)(uu & 0xffffffffull));
                    acc[2 * v + 1] += __uint_as_float((unsigned)(uu >> 32));
                }
            }
#pragma unroll
            for (int c = 0; c < NCLS; ++c) {
                acc[c] += __shfl_xor(acc[c], 1, 64);
                acc[c] += __shfl_xor(acc[c], 2, 64);
                acc[c] *= (1.f / 16.f);                // msg
            }
            float ref[5];
#pragma unroll
            for (int i = 0; i < 5; ++i) {
                float s = lsr[i];
#pragma unroll
                for (int k = 0; k < NCLS; ++k) s += acc[k] * Ws[(c0 + i) * NCLS + k];  // x@W^T
                ref[i] = s;
            }
            float mx = ref[0];
#pragma unroll
            for (int i = 1; i < 5; ++i) mx = fmaxf(mx, ref[i]);
            mx = fmaxf(mx, __shfl_xor(mx, 1, 64));
            mx = fmaxf(mx, __shfl_xor(mx, 2, 64));
            float ex[5];
            float ps = 0.f;
#pragma unroll
            for (int i = 0; i < 5; ++i) { ex[i] = __expf(ref[i] - mx); ps += ex[i]; }
            ps += __shfl_xor(ps, 1, 64);
            ps += __shfl_xor(ps, 2, 64);
            const float inv = 1.f / ps;

            if (it == 2) {
                const int o = orig[p];
#pragma unroll
                for (int i = 0; i < 5; ++i) {
                    outRef[o * NCLS + c0 + i] = ref[i];
                    outQ[o * NCLS + c0 + i] = ex[i] * inv;
                }
            } else {
                float* qout = (it == 0) ? q1s : q0s;
                // coherent sc1 stores: globally visible once vmcnt retires
#pragma unroll
                for (int i = 0; i < 5; ++i)
                    __hip_atomic_store(&qout[p * NCLS + c0 + i], ex[i] * inv,
                                       __ATOMIC_RELAXED, __HIP_MEMORY_SCOPE_AGENT);
            }
        }
        if (it == 0)      { gridBarrier(bar + 0, (int)gridDim.x); qin = q1s; }
        else if (it == 1) { gridBarrier(bar + 1, (int)gridDim.x); qin = q0s; }
    }
}

// ---------------------------------------------------------------------------
extern "C" void kernel_launch(void* const* d_in, const int* in_sizes, int n_in,
                              void* d_out, int out_size, void* d_ws, size_t ws_size,
                              hipStream_t stream) {
    const float* logits = (const float*)d_in[0];   // (20000, 20)
    const float* coords = (const float*)d_in[1];   // (20000, 3)
    const float* W      = (const float*)d_in[2];   // (20, 20)
    float* out = (float*)d_out;                    // refined (400000) | q (400000)

    // workspace (~5 MB); q1s aliases out's q-region (safe: final pass reads
    // only q0s/ls/knn/orig and overwrites that region last).
    char* ws = (char*)d_ws;
    size_t off = 0;
    int* knn = (int*)(ws + off);              off += (size_t)N_PTS * KNN * 4;
    off = (off + 255) & ~(size_t)255;
    float* ls = (float*)(ws + off);           off += (size_t)N_PTS * NCLS * 4;
    off = (off + 255) & ~(size_t)255;
    float* q0s = (float*)(ws + off);          off += (size_t)N_PTS * NCLS * 4;
    off = (off + 255) & ~(size_t)255;
    float4* sortedPts = (float4*)(ws + off);  off += (size_t)N_PTS * 16;
    off = (off + 255) & ~(size_t)255;
    int* orig = (int*)(ws + off);             off += (size_t)N_PTS * 4;
    off = (off + 255) & ~(size_t)255;
    int* cellCount = (int*)(ws + off);        off += (size_t)(NCELLS + 4) * 4;
    int* doneCtr   = cellCount + NCELLS;      // zeroed with cellCount
    int* readyFlag = cellCount + NCELLS + 1;
    int* bar       = cellCount + NCELLS + 2;  // 2 counters
    off = (off + 255) & ~(size_t)255;
    int* cellStart = (int*)(ws + off);        off += (size_t)(NCELLS + 1) * 4;
    off = (off + 255) & ~(size_t)255;
    int* cellCursor = (int*)(ws + off);
    float* q1s = out + N_PTS * NCLS;

    const int threads = 256;
    const int pblocks = (N_PTS + threads - 1) / threads;      // 79
    const int cblocks = (4 * N_PTS + threads - 1) / threads;  // 313

    hipMemsetAsync(cellCount, 0, (NCELLS + 4) * sizeof(int), stream);
    build_kernel<<<pblocks, threads, 0, stream>>>(coords, logits, cellCount, doneCtr,
                                                  readyFlag, cellStart, cellCursor,
                                                  sortedPts, orig, ls, q0s);
    knn_kernel<<<NCELLS * 2, threads, 0, stream>>>(sortedPts, cellStart, knn);
    crf3_kernel<<<cblocks, threads, 0, stream>>>(ls, W, knn, q0s, q1s, orig,
                                                 out, out + N_PTS * NCLS, bar);
}

// Round 3
// 157.226 us; speedup vs baseline: 1.2518x; 1.2321x over previous
//
#include <hip/hip_runtime.h>

#define N_PTS 20000
#define NCLS 20
#define KNN 16
#define GRID 12
#define NCELLS (GRID * GRID * GRID)
#define HCELL (1.0f / (float)GRID)
#define CAP 64             // slots per cell; lambda=11.6 -> P(overflow) ~ 1e-20
#define CAND_CAP 640       // worst staged block: bd>=2 hs=2 clipped 45 cells E~522 +5sig
#define KEY_CAP 128        // filtered keys per point (E~26; taumax corner E~48, edge E~96)
#define R_TARGET 0.0680f   // radius giving E[cnt]~26 in the interior

__device__ __forceinline__ int cell1d(float v) {
    int c = (int)(v * (float)GRID);
    return min(max(c, 0), GRID - 1);
}

// ---------------------------------------------------------------------------
// SYNC-FREE build: count+scatter collapse into one atomicAdd per point with a
// fixed-capacity cell layout (no scan, no handshake, no spin -- round 1/2
// showed grid-wide spins cost ~30us each on this chip). Also computes
// softmax(logits) -> q0 in ORIGINAL point order (coalesced).
// ---------------------------------------------------------------------------
__global__ __launch_bounds__(256) void scatter_kernel(const float* __restrict__ coords,
                                                      const float* __restrict__ logits,
                                                      int* __restrict__ cnt,
                                                      float4* __restrict__ cellPts,
                                                      float* __restrict__ q0) {
    const int p = blockIdx.x * blockDim.x + threadIdx.x;
    if (p >= N_PTS) return;
    const float x = coords[3 * p + 0];
    const float y = coords[3 * p + 1];
    const float z = coords[3 * p + 2];
    const int c = (cell1d(z) * GRID + cell1d(y)) * GRID + cell1d(x);
    const int pos = atomicAdd(&cnt[c], 1);
    if (pos < CAP)   // deterministically never false for this input
        cellPts[c * CAP + pos] = make_float4(x, y, z, __uint_as_float((unsigned)p));

    const float4* l4 = (const float4*)(logits + p * NCLS);
    float v[NCLS];
#pragma unroll
    for (int u = 0; u < 5; ++u) {
        const float4 a = l4[u];
        v[4 * u + 0] = a.x; v[4 * u + 1] = a.y;
        v[4 * u + 2] = a.z; v[4 * u + 3] = a.w;
    }
    float mx = v[0];
#pragma unroll
    for (int cc = 1; cc < NCLS; ++cc) mx = fmaxf(mx, v[cc]);
    float sum = 0.f;
#pragma unroll
    for (int cc = 0; cc < NCLS; ++cc) { v[cc] = __expf(v[cc] - mx); sum += v[cc]; }
    const float inv = 1.f / sum;
    float4* q4 = (float4*)(q0 + p * NCLS);
#pragma unroll
    for (int u = 0; u < 5; ++u)
        q4[u] = make_float4(v[4 * u] * inv, v[4 * u + 1] * inv,
                            v[4 * u + 2] * inv, v[4 * u + 3] * inv);
}

// ---------------------------------------------------------------------------
// Rare exact fallback: wave-cooperative ladder over the fixed-cap cell grid.
// Only ~100-200 face-cell points (Poisson undercount) ever reach this.
// Ids in keys / knn_out rows are ORIGINAL point ids.
// ---------------------------------------------------------------------------
__device__ void knn_ladder(const float4* __restrict__ cellPts,
                           const int* __restrict__ cnt,
                           const float4 qp, const int s, int hw,
                           unsigned long long* keys, const int lane,
                           int* __restrict__ knn_out) {
    const unsigned long long laneLt = (1ull << lane) - 1ull;
    const int cx = cell1d(qp.x), cy = cell1d(qp.y), cz = cell1d(qp.z);
    float g = 0.9995f * (float)hw * HCELL;
    float tau = g * g;
    int m = 0;
    for (int att = 0; att < 16; ++att) {
        m = 0;
        const int xlo = max(cx - hw, 0), xhi = min(cx + hw, GRID - 1);
        const int ylo = max(cy - hw, 0), yhi = min(cy + hw, GRID - 1);
        const int zlo = max(cz - hw, 0), zhi = min(cz + hw, GRID - 1);
        for (int zz = zlo; zz <= zhi; ++zz)
            for (int yy = ylo; yy <= yhi; ++yy)
                for (int xx = xlo; xx <= xhi; ++xx) {
                    const int cellc = (zz * GRID + yy) * GRID + xx;
                    const int n = min(cnt[cellc], CAP);
                    const int base = cellc * CAP;
                    for (int j0 = 0; j0 < n; j0 += 64) {
                        const int j = j0 + lane;
                        const bool jv = j < n;
                        const float4 pt = cellPts[base + (jv ? j : 0)];
                        const float dx = pt.x - qp.x, dy = pt.y - qp.y, dz = pt.z - qp.z;
                        const float d2 = dx * dx + dy * dy + dz * dz;
                        const bool take = jv && (d2 < tau);
                        const unsigned long long mm = __ballot(take);
                        if (take) {
                            const int pos = m + (int)__popcll(mm & laneLt);
                            if (pos < KEY_CAP)
                                keys[pos] = (((unsigned long long)__float_as_uint(d2)) << 32) |
                                            (unsigned long long)__float_as_uint(pt.w);
                        }
                        m += (int)__popcll(mm);
                    }
                }
        if (m >= KNN && m <= KEY_CAP) break;
        if (m < KNN) {
            if (hw < GRID - 1) { ++hw; g = 0.9995f * (float)hw * HCELL; tau = g * g; }
            else tau *= 2.5f;
        } else {
            tau *= 0.6f;
        }
    }
    const int mm2 = min(m, KEY_CAP);
    const unsigned long long k0 = (lane < mm2) ? keys[lane] : ~0ull;
    const unsigned long long k1 = (lane + 64 < mm2) ? keys[lane + 64] : ~0ull;
    int r0 = 0, r1 = 0;
    for (int j = 0; j < mm2; ++j) {
        const unsigned long long kj = keys[j];
        r0 += (kj < k0); r1 += (kj < k1);
    }
    if (lane < mm2 && r0 < KNN)      knn_out[s * KNN + r0] = (int)(unsigned)(k0 & 0xffffffffull);
    if (lane + 64 < mm2 && r1 < KNN) knn_out[s * KNN + r1] = (int)(unsigned)(k1 & 0xffffffffull);
}

// ---------------------------------------------------------------------------
// kNN on the fixed-cap grid: TWO blocks per cell (3456 blocks, 14.3KB LDS).
// Interior/face cells stage the 3^3 halo; edge/corner (bd>=2) the clipped
// 5^3 (<=45 runs <= 64 lanes). Staged region is EXACT for radius <= hs*h.
// Filter d2<tau, rank-by-broadcast top-16. Ids are ORIGINAL point ids.
// ---------------------------------------------------------------------------
__global__ __launch_bounds__(256) void knn_kernel(const float4* __restrict__ cellPts,
                                                  const int* __restrict__ cnt,
                                                  int* __restrict__ knn_out) {
    __shared__ float4 cand[CAND_CAP];                 // 10.24 KB
    __shared__ unsigned long long keys[4][KEY_CAP];   // 4 KB
    const int lane = threadIdx.x & 63;
    const int wave = threadIdx.x >> 6;
    const int c = blockIdx.x >> 1;
    const int half = blockIdx.x & 1;
    const int cz = c / (GRID * GRID);
    const int cy = (c / GRID) % GRID;
    const int cx = c % GRID;
    const int npts = min(cnt[c], CAP);
    if (npts <= 0) return;
    const int bd = (cx == 0 || cx == GRID - 1) + (cy == 0 || cy == GRID - 1) +
                   (cz == 0 || cz == GRID - 1);
    const int hs = (bd >= 2) ? 2 : 1;                 // staging halo width
    const unsigned long long laneLt = (1ull << lane) - 1ull;

    const int xlo = max(cx - hs, 0), xhi = min(cx + hs, GRID - 1);
    const int ylo = max(cy - hs, 0), yhi = min(cy + hs, GRID - 1);
    const int zlo = max(cz - hs, 0), zhi = min(cz + hs, GRID - 1);
    const int nx = xhi - xlo + 1;
    const int ny = yhi - ylo + 1;
    const int nruns = (zhi - zlo + 1) * ny * nx;      // <= 45 single-cell runs

    int beg = 0, len = 0;
    if (lane < nruns) {
        const int xx = xlo + lane % nx;
        const int yy = ylo + (lane / nx) % ny;
        const int zz = zlo + lane / (nx * ny);
        const int cellc = (zz * GRID + yy) * GRID + xx;
        beg = cellc * CAP;
        len = min(cnt[cellc], CAP);
    }
    int off = len;
#pragma unroll
    for (int sh = 1; sh < 64; sh <<= 1) {             // full 64-lane scan (nruns<=45)
        const int o = __shfl_up(off, sh, 64);
        if (lane >= sh) off += o;
    }
    const int nc = __shfl(off, nruns - 1);
    off -= len;                                        // exclusive
    const int ownRun = ((cz - zlo) * ny + (cy - ylo)) * nx + (cx - xlo);
    const int ownOff = __shfl(off, ownRun);

    if (nc <= CAND_CAP) {
        for (int r = wave; r < nruns; r += 4) {
            const int rb = __shfl(beg, r);
            const int rl = __shfl(len, r);
            const int ro = __shfl(off, r);
            for (int i = lane; i < rl; i += 64)
                cand[ro + i] = cellPts[rb + i];       // .w = ORIGINAL id
        }
    }
    __syncthreads();

    if (nc > CAND_CAP) {                               // ~never (>5 sigma)
        for (int idx = 2 * wave + half; idx < npts; idx += 8) {
            const float4 qp = cellPts[c * CAP + idx];
            knn_ladder(cellPts, cnt, qp, (int)__float_as_uint(qp.w),
                       hs, keys[wave], lane, knn_out);
        }
        return;
    }

    const float taumaxr = 0.9995f * (float)hs * HCELL;
    const float taumax = taumaxr * taumaxr;

    for (int idx = 2 * wave + half; idx < npts; idx += 8) {
        const float4 qp = cand[ownOff + idx];
        const int s = (int)__float_as_uint(qp.w);      // ORIGINAL query id
        // boundary-corrected tau targeting E[cnt]~26, capped at coverage hs*h
        float r = R_TARGET;
        const float inv2r = 0.5f / r;
        const float fx = (fminf(qp.x + r, 1.f) - fmaxf(qp.x - r, 0.f)) * inv2r;
        const float fy = (fminf(qp.y + r, 1.f) - fmaxf(qp.y - r, 0.f)) * inv2r;
        const float fz = (fminf(qp.z + r, 1.f) - fmaxf(qp.z - r, 0.f)) * inv2r;
        const float f = fmaxf(fx * fy * fz, 0.05f);
        r = R_TARGET * __powf(f, -0.33333334f);
        float tau = fminf(r * r, taumax);
        bool triedMax = (tau >= taumax * 0.999f);

        int m = 0;
        bool ok = false;
        for (int att = 0; att < 5 && !ok; ++att) {
            m = 0;
            for (int j0 = 0; j0 < nc; j0 += 64) {
                const int j = j0 + lane;
                float d2 = 1e30f;
                unsigned pw = 0;
                if (j < nc) {
                    const float4 pt = cand[j];
                    const float dx = pt.x - qp.x, dy = pt.y - qp.y, dz = pt.z - qp.z;
                    d2 = dx * dx + dy * dy + dz * dz;
                    pw = __float_as_uint(pt.w);
                }
                const bool take = d2 < tau;
                const unsigned long long mm = __ballot(take);
                if (take) {
                    const int pos = m + (int)__popcll(mm & laneLt);
                    if (pos < KEY_CAP)
                        keys[wave][pos] =
                            (((unsigned long long)__float_as_uint(d2)) << 32) |
                            (unsigned long long)pw;
                }
                m += (int)__popcll(mm);
            }
            if (m >= KNN && m <= KEY_CAP) ok = true;
            else if (m < KNN) {
                if (triedMax) break;                   // needs radius > hs*h -> ladder
                tau = taumax; triedMax = true;
            } else tau *= 0.6f;
        }
        if (!ok) {                                     // rare Poisson-tail points
            knn_ladder(cellPts, cnt, qp, s, hs + 1, keys[wave], lane, knn_out);
            continue;
        }
        const unsigned long long k0 = (lane < m) ? keys[wave][lane] : ~0ull;
        const unsigned long long k1 = (lane + 64 < m) ? keys[wave][lane + 64] : ~0ull;
        int r0 = 0, r1 = 0;
        for (int j = 0; j < m; ++j) {
            const unsigned long long kj = keys[wave][j];   // LDS broadcast
            r0 += (kj < k0); r1 += (kj < k1);
        }
        if (lane < m && r0 < KNN)      knn_out[s * KNN + r0] = (int)(unsigned)(k0 & 0xffffffffull);
        if (lane + 64 < m && r1 < KNN) knn_out[s * KNN + r1] = (int)(unsigned)(k1 & 0xffffffffull);
    }
}

// ---------------------------------------------------------------------------
// CRF iteration, ORIGINAL point order, 4 lanes/point. Reads logits directly
// (no ls copy); knn rows hold original ids. Proven round-0 structure.
// ---------------------------------------------------------------------------
__global__ __launch_bounds__(256) void crf_iter_kernel(const float* __restrict__ logits,
                                                       const float* __restrict__ W,
                                                       const int* __restrict__ knn,
                                                       const float* __restrict__ qin,
                                                       float* __restrict__ qout,
                                                       float* __restrict__ outRef,
                                                       float* __restrict__ outQ) {
    __shared__ float Ws[NCLS * NCLS];
    for (int i = threadIdx.x; i < NCLS * NCLS; i += blockDim.x) Ws[i] = W[i];
    __syncthreads();
    const int t = blockIdx.x * blockDim.x + threadIdx.x;
    const int p = t >> 2;
    const int qtr = t & 3;
    if (p >= N_PTS) return;

    float acc[NCLS];
#pragma unroll
    for (int c = 0; c < NCLS; ++c) acc[c] = 0.f;

    const int4 k4 = ((const int4*)(knn + p * KNN))[qtr];
    const int ids[4] = {k4.x, k4.y, k4.z, k4.w};
#pragma unroll
    for (int u = 0; u < 4; ++u) {
        unsigned id = (unsigned)ids[u];
        if (id >= N_PTS) id = 0;        // safety clamp (unreachable)
        const float4* r4 = (const float4*)(qin + id * NCLS);
#pragma unroll
        for (int v = 0; v < 5; ++v) {
            const float4 a = r4[v];
            acc[4 * v + 0] += a.x; acc[4 * v + 1] += a.y;
            acc[4 * v + 2] += a.z; acc[4 * v + 3] += a.w;
        }
    }
#pragma unroll
    for (int c = 0; c < NCLS; ++c) {
        acc[c] += __shfl_xor(acc[c], 1, 64);
        acc[c] += __shfl_xor(acc[c], 2, 64);
        acc[c] *= (1.f / 16.f);          // msg
    }

    const int c0 = qtr * 5;
    float ref[5];
#pragma unroll
    for (int i = 0; i < 5; ++i) {
        float s = logits[p * NCLS + c0 + i];
#pragma unroll
        for (int k = 0; k < NCLS; ++k) s += acc[k] * Ws[(c0 + i) * NCLS + k];  // x@W^T
        ref[i] = s;
    }

    float mx = ref[0];
#pragma unroll
    for (int i = 1; i < 5; ++i) mx = fmaxf(mx, ref[i]);
    mx = fmaxf(mx, __shfl_xor(mx, 1, 64));
    mx = fmaxf(mx, __shfl_xor(mx, 2, 64));
    float ex[5];
    float ps = 0.f;
#pragma unroll
    for (int i = 0; i < 5; ++i) { ex[i] = __expf(ref[i] - mx); ps += ex[i]; }
    ps += __shfl_xor(ps, 1, 64);
    ps += __shfl_xor(ps, 2, 64);
    const float inv = 1.f / ps;

    if (outRef != nullptr) {
#pragma unroll
        for (int i = 0; i < 5; ++i) {
            outRef[p * NCLS + c0 + i] = ref[i];
            outQ[p * NCLS + c0 + i] = ex[i] * inv;
        }
    } else {
#pragma unroll
        for (int i = 0; i < 5; ++i) qout[p * NCLS + c0 + i] = ex[i] * inv;
    }
}

// ---------------------------------------------------------------------------
extern "C" void kernel_launch(void* const* d_in, const int* in_sizes, int n_in,
                              void* d_out, int out_size, void* d_ws, size_t ws_size,
                              hipStream_t stream) {
    const float* logits = (const float*)d_in[0];   // (20000, 20)
    const float* coords = (const float*)d_in[1];   // (20000, 3)
    const float* W      = (const float*)d_in[2];   // (20, 20)
    float* out = (float*)d_out;                    // refined (400000) | q (400000)

    // workspace (~4.7 MB); q1 aliases out's q-region (safe: final pass reads
    // only q0/logits/knn and overwrites that region last).
    char* ws = (char*)d_ws;
    size_t off = 0;
    int* knn = (int*)(ws + off);              off += (size_t)N_PTS * KNN * 4;
    off = (off + 255) & ~(size_t)255;
    float* q0 = (float*)(ws + off);           off += (size_t)N_PTS * NCLS * 4;
    off = (off + 255) & ~(size_t)255;
    float4* cellPts = (float4*)(ws + off);    off += (size_t)NCELLS * CAP * 16;
    off = (off + 255) & ~(size_t)255;
    int* cnt = (int*)(ws + off);              off += (size_t)NCELLS * 4;
    float* q1 = out + N_PTS * NCLS;

    const int threads = 256;
    const int pblocks = (N_PTS + threads - 1) / threads;      // 79
    const int cblocks = (4 * N_PTS + threads - 1) / threads;  // 313

    hipMemsetAsync(cnt, 0, NCELLS * sizeof(int), stream);
    scatter_kernel<<<pblocks, threads, 0, stream>>>(coords, logits, cnt, cellPts, q0);
    knn_kernel<<<NCELLS * 2, threads, 0, stream>>>(cellPts, cnt, knn);
    crf_iter_kernel<<<cblocks, threads, 0, stream>>>(logits, W, knn, q0, q1,
                                                     nullptr, nullptr);
    crf_iter_kernel<<<cblocks, threads, 0, stream>>>(logits, W, knn, q1, q0,
                                                     nullptr, nullptr);
    crf_iter_kernel<<<cblocks, threads, 0, stream>>>(logits, W, knn, q0, nullptr,
                                                     out, out + N_PTS * NCLS);
}

// Round 4
// 149.406 us; speedup vs baseline: 1.3174x; 1.0523x over previous
//
#include <hip/hip_runtime.h>

#define N_PTS 20000
#define NCLS 20
#define KNN 16
#define GRID 12
#define NCELLS (GRID * GRID * GRID)
#define HCELL (1.0f / (float)GRID)
#define CAND_CAP 640       // worst staged block: bd>=2 hs=2 clipped 5^3 E~521 +5sig
#define KEY_CAP 128        // filtered keys per point (E~26; taumax corner E~48, edge E~96)
#define R_TARGET 0.0680f   // radius giving E[cnt]~26 in the interior
#define QCAP 8192          // failed-point queue capacity (E~250)

__device__ __forceinline__ int cell1d(float v) {
    int c = (int)(v * (float)GRID);
    return min(max(c, 0), GRID - 1);
}

// ---------------------------------------------------------------------------
// Count (grid-wide atomics) + fused scan: last block performs the 1728-cell
// exclusive scan (agent-scope loads; done-counter, NO spin -- non-last blocks
// return immediately). Round-0 proven.
// ---------------------------------------------------------------------------
__global__ __launch_bounds__(256) void count_scan_kernel(const float* __restrict__ coords,
                                                         int* __restrict__ cellCount,
                                                         int* __restrict__ doneCtr,
                                                         int* __restrict__ cellStart,
                                                         int* __restrict__ cellCursor) {
    const int p = blockIdx.x * blockDim.x + threadIdx.x;
    if (p < N_PTS) {
        const int cx = cell1d(coords[3 * p + 0]);
        const int cy = cell1d(coords[3 * p + 1]);
        const int cz = cell1d(coords[3 * p + 2]);
        atomicAdd(&cellCount[(cz * GRID + cy) * GRID + cx], 1);
    }
    __threadfence();
    __syncthreads();
    __shared__ bool isLast;
    if (threadIdx.x == 0)
        isLast = (atomicAdd(doneCtr, 1) == (int)gridDim.x - 1);
    __syncthreads();
    if (!isLast) return;

    __shared__ int part[256];
    const int t = threadIdx.x;
    const int base = t * 7;                   // 256*7 = 1792 >= 1728
    int local[7];
    int s = 0;
#pragma unroll
    for (int i = 0; i < 7; ++i) {
        const int c = base + i;
        const int v = (c < NCELLS)
            ? __hip_atomic_load(&cellCount[c], __ATOMIC_RELAXED, __HIP_MEMORY_SCOPE_AGENT)
            : 0;
        local[i] = s;
        s += v;
    }
    part[t] = s;
    __syncthreads();
    for (int off = 1; off < 256; off <<= 1) {
        const int v = part[t] + ((t >= off) ? part[t - off] : 0);
        __syncthreads();
        part[t] = v;
        __syncthreads();
    }
    const int excl = (t > 0) ? part[t - 1] : 0;
#pragma unroll
    for (int i = 0; i < 7; ++i) {
        const int c = base + i;
        if (c < NCELLS) {
            cellStart[c] = excl + local[i];
            cellCursor[c] = excl + local[i];
        }
    }
    if (t == 255) cellStart[NCELLS] = part[255];
}

// ---------------------------------------------------------------------------
// Scatter (counting sort) + gather logits row + FUSED softmax -> q0s, ls.
// Round-0 proven.
// ---------------------------------------------------------------------------
__global__ __launch_bounds__(256) void scatter_kernel(const float* __restrict__ coords,
                                                      const float* __restrict__ logits,
                                                      int* __restrict__ cellCursor,
                                                      float4* __restrict__ sortedPts,
                                                      int* __restrict__ orig,
                                                      float* __restrict__ ls,
                                                      float* __restrict__ q0s) {
    const int p = blockIdx.x * blockDim.x + threadIdx.x;
    if (p >= N_PTS) return;
    const float x = coords[3 * p + 0];
    const float y = coords[3 * p + 1];
    const float z = coords[3 * p + 2];
    const int c = (cell1d(z) * GRID + cell1d(y)) * GRID + cell1d(x);
    const int pos = atomicAdd(&cellCursor[c], 1);
    sortedPts[pos] = make_float4(x, y, z, __uint_as_float((unsigned)p));
    orig[pos] = p;
    const float4* l4 = (const float4*)(logits + p * NCLS);
    float v[NCLS];
#pragma unroll
    for (int u = 0; u < 5; ++u) {
        const float4 a = l4[u];
        v[4 * u + 0] = a.x; v[4 * u + 1] = a.y;
        v[4 * u + 2] = a.z; v[4 * u + 3] = a.w;
    }
    float4* d4 = (float4*)(ls + pos * NCLS);
#pragma unroll
    for (int u = 0; u < 5; ++u)
        d4[u] = make_float4(v[4 * u], v[4 * u + 1], v[4 * u + 2], v[4 * u + 3]);
    float mx = v[0];
#pragma unroll
    for (int cc = 1; cc < NCLS; ++cc) mx = fmaxf(mx, v[cc]);
    float sum = 0.f;
#pragma unroll
    for (int cc = 0; cc < NCLS; ++cc) { v[cc] = __expf(v[cc] - mx); sum += v[cc]; }
    const float inv = 1.f / sum;
    float4* q4 = (float4*)(q0s + pos * NCLS);
#pragma unroll
    for (int u = 0; u < 5; ++u)
        q4[u] = make_float4(v[4 * u] * inv, v[4 * u + 1] * inv,
                            v[4 * u + 2] * inv, v[4 * u + 3] * inv);
}

// ---------------------------------------------------------------------------
// Exact fallback: wave-cooperative global-memory ladder (hw growing).
// Now runs ONLY in ladder_kernel (one wave per failed point, all parallel).
// ---------------------------------------------------------------------------
__device__ void knn_ladder(const float4* __restrict__ sortedPts,
                           const int* __restrict__ cellStart,
                           const float4 qp, const int s, int hw,
                           unsigned long long* keys, const int lane,
                           int* __restrict__ knn_out) {
    const unsigned long long laneLt = (1ull << lane) - 1ull;
    const int cx = cell1d(qp.x), cy = cell1d(qp.y), cz = cell1d(qp.z);
    float g = 0.9995f * (float)hw * HCELL;
    float tau = g * g;
    int cnt = 0;
    for (int att = 0; att < 16; ++att) {
        cnt = 0;
        const int xlo = max(cx - hw, 0), xhi = min(cx + hw, GRID - 1);
        const int ylo = max(cy - hw, 0), yhi = min(cy + hw, GRID - 1);
        const int zlo = max(cz - hw, 0), zhi = min(cz + hw, GRID - 1);
        for (int zz = zlo; zz <= zhi; ++zz) {
            for (int yy = ylo; yy <= yhi; ++yy) {
                const int rowc = (zz * GRID + yy) * GRID;
                const int beg = cellStart[rowc + xlo];
                const int end = cellStart[rowc + xhi + 1];
                for (int j0 = beg; j0 < end; j0 += 64) {
                    const int j = j0 + lane;
                    const bool jv = j < end;
                    const float4 pt = sortedPts[jv ? j : beg];
                    const float dx = pt.x - qp.x, dy = pt.y - qp.y, dz = pt.z - qp.z;
                    const float d2 = dx * dx + dy * dy + dz * dz;
                    const bool take = jv && (d2 < tau);
                    const unsigned long long mm = __ballot(take);
                    if (take) {
                        const int pos = cnt + (int)__popcll(mm & laneLt);
                        if (pos < KEY_CAP)
                            keys[pos] = (((unsigned long long)__float_as_uint(d2)) << 32) |
                                        (unsigned long long)(unsigned)j;
                    }
                    cnt += (int)__popcll(mm);
                }
            }
        }
        if (cnt >= KNN && cnt <= KEY_CAP) break;
        if (cnt < KNN) {
            if (hw < GRID - 1) { ++hw; g = 0.9995f * (float)hw * HCELL; tau = g * g; }
            else tau *= 2.5f;
        } else {
            tau *= 0.6f;
        }
    }
    const int m = min(cnt, KEY_CAP);
    const unsigned long long k0 = (lane < m) ? keys[lane] : ~0ull;
    const unsigned long long k1 = (lane + 64 < m) ? keys[lane + 64] : ~0ull;
    int r0 = 0, r1 = 0;
    for (int j = 0; j < m; ++j) {
        const unsigned long long kj = keys[j];
        r0 += (kj < k0); r1 += (kj < k1);
    }
    if (lane < m && r0 < KNN)      knn_out[s * KNN + r0] = (int)(unsigned)(k0 & 0xffffffffull);
    if (lane + 64 < m && r1 < KNN) knn_out[s * KNN + r1] = (int)(unsigned)(k1 & 0xffffffffull);
}

// ---------------------------------------------------------------------------
// kNN fast path: TWO blocks per cell (3456 blocks, 14.3KB LDS). Round-0
// structure, but fast-path failures are ENQUEUED (lane-0 atomicAdd) instead
// of running the serial ladder inline -- the inline ladders were the 65us
// kernel's load-imbalance tail (VALUBusy 27%, Occupancy 20%).
// ---------------------------------------------------------------------------
__global__ __launch_bounds__(256) void knn_kernel(const float4* __restrict__ sortedPts,
                                                  const int* __restrict__ cellStart,
                                                  int* __restrict__ knn_out,
                                                  int* __restrict__ qn,
                                                  int* __restrict__ queue) {
    __shared__ float4 cand[CAND_CAP];                 // 10.24 KB
    __shared__ unsigned long long keys[4][KEY_CAP];   // 4 KB
    const int lane = threadIdx.x & 63;
    const int wave = threadIdx.x >> 6;
    const int c = blockIdx.x >> 1;
    const int half = blockIdx.x & 1;
    const int cz = c / (GRID * GRID);
    const int cy = (c / GRID) % GRID;
    const int cx = c % GRID;
    const int pbeg = cellStart[c];
    const int pend = cellStart[c + 1];
    const int npts = pend - pbeg;
    if (npts <= 0) return;
    const int bd = (cx == 0 || cx == GRID - 1) + (cy == 0 || cy == GRID - 1) +
                   (cz == 0 || cz == GRID - 1);
    const int hs = (bd >= 2) ? 2 : 1;                 // staging halo width
    const unsigned long long laneLt = (1ull << lane) - 1ull;

    const int xlo = max(cx - hs, 0), xhi = min(cx + hs, GRID - 1);
    const int ylo = max(cy - hs, 0), yhi = min(cy + hs, GRID - 1);
    const int zlo = max(cz - hs, 0), zhi = min(cz + hs, GRID - 1);
    const int ny = yhi - ylo + 1;
    const int nruns = (zhi - zlo + 1) * ny;           // <= 25 x-contiguous runs

    int beg = 0, len = 0;
    if (lane < nruns) {
        const int zz = zlo + lane / ny;
        const int yy = ylo + lane % ny;
        const int rowc = (zz * GRID + yy) * GRID;
        beg = cellStart[rowc + xlo];
        len = cellStart[rowc + xhi + 1] - beg;
    }
    int off = len;
#pragma unroll
    for (int sh = 1; sh < 32; sh <<= 1) {
        const int o = __shfl_up(off, sh, 64);
        if (lane >= sh) off += o;
    }
    const int nc = __shfl(off, nruns - 1);
    off -= len;                                        // exclusive
    const int ownRun = (cz - zlo) * ny + (cy - ylo);
    const int ownOff = __shfl(off, ownRun) + (pbeg - __shfl(beg, ownRun));

    if (nc <= CAND_CAP) {
        for (int r = wave; r < nruns; r += 4) {
            const int rb = __shfl(beg, r);
            const int rl = __shfl(len, r);
            const int ro = __shfl(off, r);
            for (int i = lane; i < rl; i += 64) {
                float4 pt = sortedPts[rb + i];
                pt.w = __uint_as_float((unsigned)(rb + i));
                cand[ro + i] = pt;
            }
        }
    }
    __syncthreads();

    if (nc > CAND_CAP) {                               // ~never (>5 sigma)
        for (int idx = 2 * wave + half; idx < npts; idx += 8)
            if (lane == 0) {
                const int sl = atomicAdd(qn, 1);
                if (sl < QCAP) queue[sl] = pbeg + idx;
            }
        return;
    }

    const float taumaxr = 0.9995f * (float)hs * HCELL;
    const float taumax = taumaxr * taumaxr;

    for (int idx = 2 * wave + half; idx < npts; idx += 8) {
        const int s = pbeg + idx;
        const float4 qp = cand[ownOff + idx];
        // boundary-corrected tau targeting E[cnt]~26, capped at coverage hs*h
        float r = R_TARGET;
        const float inv2r = 0.5f / r;
        const float fx = (fminf(qp.x + r, 1.f) - fmaxf(qp.x - r, 0.f)) * inv2r;
        const float fy = (fminf(qp.y + r, 1.f) - fmaxf(qp.y - r, 0.f)) * inv2r;
        const float fz = (fminf(qp.z + r, 1.f) - fmaxf(qp.z - r, 0.f)) * inv2r;
        const float f = fmaxf(fx * fy * fz, 0.05f);
        r = R_TARGET * __powf(f, -0.33333334f);
        float tau = fminf(r * r, taumax);
        bool triedMax = (tau >= taumax * 0.999f);

        int cnt = 0;
        bool ok = false;
        for (int att = 0; att < 5 && !ok; ++att) {
            cnt = 0;
            for (int j0 = 0; j0 < nc; j0 += 64) {
                const int j = j0 + lane;
                float d2 = 1e30f;
                unsigned pw = 0;
                if (j < nc) {
                    const float4 pt = cand[j];
                    const float dx = pt.x - qp.x, dy = pt.y - qp.y, dz = pt.z - qp.z;
                    d2 = dx * dx + dy * dy + dz * dz;
                    pw = __float_as_uint(pt.w);
                }
                const bool take = d2 < tau;
                const unsigned long long mm = __ballot(take);
                if (take) {
                    const int pos = cnt + (int)__popcll(mm & laneLt);
                    if (pos < KEY_CAP)
                        keys[wave][pos] =
                            (((unsigned long long)__float_as_uint(d2)) << 32) |
                            (unsigned long long)pw;
                }
                cnt += (int)__popcll(mm);
            }
            if (cnt >= KNN && cnt <= KEY_CAP) ok = true;
            else if (cnt < KNN) {
                if (triedMax) break;                   // needs radius > hs*h -> queue
                tau = taumax; triedMax = true;
            } else tau *= 0.6f;
        }
        if (!ok) {                                     // rare Poisson-tail points
            if (lane == 0) {
                const int sl = atomicAdd(qn, 1);
                if (sl < QCAP) queue[sl] = s;
            }
            continue;
        }
        const int m = cnt;
        const unsigned long long k0 = (lane < m) ? keys[wave][lane] : ~0ull;
        const unsigned long long k1 = (lane + 64 < m) ? keys[wave][lane + 64] : ~0ull;
        int r0 = 0, r1 = 0;
        for (int j = 0; j < m; ++j) {
            const unsigned long long kj = keys[wave][j];   // LDS broadcast
            r0 += (kj < k0); r1 += (kj < k1);
        }
        if (lane < m && r0 < KNN)      knn_out[s * KNN + r0] = (int)(unsigned)(k0 & 0xffffffffull);
        if (lane + 64 < m && r1 < KNN) knn_out[s * KNN + r1] = (int)(unsigned)(k1 & 0xffffffffull);
    }
}

// ---------------------------------------------------------------------------
// Ladder kernel: one WAVE per queued point, grid-stride. All ~250 ladders run
// in parallel instead of serializing inside unlucky knn blocks.
// ---------------------------------------------------------------------------
__global__ __launch_bounds__(256) void ladder_kernel(const float4* __restrict__ sortedPts,
                                                     const int* __restrict__ cellStart,
                                                     const int* __restrict__ qn,
                                                     const int* __restrict__ queue,
                                                     int* __restrict__ knn_out) {
    __shared__ unsigned long long keys[4][KEY_CAP];   // 4 KB
    const int lane = threadIdx.x & 63;
    const int wave = threadIdx.x >> 6;
    const int gw = blockIdx.x * 4 + wave;
    const int nw = gridDim.x * 4;
    const int n = min(qn[0], QCAP);
    for (int i = gw; i < n; i += nw) {
        const int s = queue[i];
        const float4 qp = sortedPts[s];
        const int cx = cell1d(qp.x), cy = cell1d(qp.y), cz = cell1d(qp.z);
        const int bd = (cx == 0 || cx == GRID - 1) + (cy == 0 || cy == GRID - 1) +
                       (cz == 0 || cz == GRID - 1);
        const int hs = (bd >= 2) ? 2 : 1;
        knn_ladder(sortedPts, cellStart, qp, s, hs + 1, keys[wave], lane, knn_out);
    }
}

// ---------------------------------------------------------------------------
// CRF iteration, SORTED space, 4 lanes/point. Round-0 proven.
// ---------------------------------------------------------------------------
__global__ __launch_bounds__(256) void crf_iter_kernel(const float* __restrict__ ls,
                                                       const float* __restrict__ W,
                                                       const int* __restrict__ knn,
                                                       const float* __restrict__ qin,
                                                       float* __restrict__ qout,
                                                       const int* __restrict__ orig,
                                                       float* __restrict__ outRef,
                                                       float* __restrict__ outQ) {
    __shared__ float Ws[NCLS * NCLS];
    for (int i = threadIdx.x; i < NCLS * NCLS; i += blockDim.x) Ws[i] = W[i];
    __syncthreads();
    const int t = blockIdx.x * blockDim.x + threadIdx.x;
    const int p = t >> 2;
    const int qtr = t & 3;
    if (p >= N_PTS) return;

    float acc[NCLS];
#pragma unroll
    for (int c = 0; c < NCLS; ++c) acc[c] = 0.f;

    const int4 k4 = ((const int4*)(knn + p * KNN))[qtr];
    const int ids[4] = {k4.x, k4.y, k4.z, k4.w};
#pragma unroll
    for (int u = 0; u < 4; ++u) {
        unsigned id = (unsigned)ids[u];
        if (id >= N_PTS) id = 0;        // safety clamp (unreachable)
        const float4* r4 = (const float4*)(qin + id * NCLS);
#pragma unroll
        for (int v = 0; v < 5; ++v) {
            const float4 a = r4[v];
            acc[4 * v + 0] += a.x; acc[4 * v + 1] += a.y;
            acc[4 * v + 2] += a.z; acc[4 * v + 3] += a.w;
        }
    }
#pragma unroll
    for (int c = 0; c < NCLS; ++c) {
        acc[c] += __shfl_xor(acc[c], 1, 64);
        acc[c] += __shfl_xor(acc[c], 2, 64);
        acc[c] *= (1.f / 16.f);          // msg
    }

    const int c0 = qtr * 5;
    float ref[5];
#pragma unroll
    for (int i = 0; i < 5; ++i) {
        float s = ls[p * NCLS + c0 + i];
#pragma unroll
        for (int k = 0; k < NCLS; ++k) s += acc[k] * Ws[(c0 + i) * NCLS + k];  // x@W^T
        ref[i] = s;
    }

    float mx = ref[0];
#pragma unroll
    for (int i = 1; i < 5; ++i) mx = fmaxf(mx, ref[i]);
    mx = fmaxf(mx, __shfl_xor(mx, 1, 64));
    mx = fmaxf(mx, __shfl_xor(mx, 2, 64));
    float ex[5];
    float ps = 0.f;
#pragma unroll
    for (int i = 0; i < 5; ++i) { ex[i] = __expf(ref[i] - mx); ps += ex[i]; }
    ps += __shfl_xor(ps, 1, 64);
    ps += __shfl_xor(ps, 2, 64);
    const float inv = 1.f / ps;

    if (outRef != nullptr) {
        const int o = orig[p];
#pragma unroll
        for (int i = 0; i < 5; ++i) {
            outRef[o * NCLS + c0 + i] = ref[i];
            outQ[o * NCLS + c0 + i] = ex[i] * inv;
        }
    } else {
#pragma unroll
        for (int i = 0; i < 5; ++i) qout[p * NCLS + c0 + i] = ex[i] * inv;
    }
}

// ---------------------------------------------------------------------------
extern "C" void kernel_launch(void* const* d_in, const int* in_sizes, int n_in,
                              void* d_out, int out_size, void* d_ws, size_t ws_size,
                              hipStream_t stream) {
    const float* logits = (const float*)d_in[0];   // (20000, 20)
    const float* coords = (const float*)d_in[1];   // (20000, 3)
    const float* W      = (const float*)d_in[2];   // (20, 20)
    float* out = (float*)d_out;                    // refined (400000) | q (400000)

    // workspace (~5 MB); q1s aliases out's q-region (safe: final pass reads
    // only q0s/ls/knn/orig and overwrites that region last).
    char* ws = (char*)d_ws;
    size_t off = 0;
    int* knn = (int*)(ws + off);              off += (size_t)N_PTS * KNN * 4;
    off = (off + 255) & ~(size_t)255;
    float* ls = (float*)(ws + off);           off += (size_t)N_PTS * NCLS * 4;
    off = (off + 255) & ~(size_t)255;
    float* q0s = (float*)(ws + off);          off += (size_t)N_PTS * NCLS * 4;
    off = (off + 255) & ~(size_t)255;
    float4* sortedPts = (float4*)(ws + off);  off += (size_t)N_PTS * 16;
    off = (off + 255) & ~(size_t)255;
    int* orig = (int*)(ws + off);             off += (size_t)N_PTS * 4;
    off = (off + 255) & ~(size_t)255;
    int* cellCount = (int*)(ws + off);        off += (size_t)(NCELLS + 2) * 4;
    int* doneCtr   = cellCount + NCELLS;      // zeroed with cellCount
    int* qn        = cellCount + NCELLS + 1;  // zeroed with cellCount
    off = (off + 255) & ~(size_t)255;
    int* cellStart = (int*)(ws + off);        off += (size_t)(NCELLS + 1) * 4;
    off = (off + 255) & ~(size_t)255;
    int* cellCursor = (int*)(ws + off);       off += (size_t)NCELLS * 4;
    off = (off + 255) & ~(size_t)255;
    int* queue = (int*)(ws + off);            off += (size_t)QCAP * 4;
    float* q1s = out + N_PTS * NCLS;

    const int threads = 256;
    const int pblocks = (N_PTS + threads - 1) / threads;      // 79
    const int cblocks = (4 * N_PTS + threads - 1) / threads;  // 313

    hipMemsetAsync(cellCount, 0, (NCELLS + 2) * sizeof(int), stream);
    count_scan_kernel<<<pblocks, threads, 0, stream>>>(coords, cellCount, doneCtr,
                                                       cellStart, cellCursor);
    scatter_kernel<<<pblocks, threads, 0, stream>>>(coords, logits, cellCursor,
                                                    sortedPts, orig, ls, q0s);
    knn_kernel<<<NCELLS * 2, threads, 0, stream>>>(sortedPts, cellStart, knn,
                                                   qn, queue);
    ladder_kernel<<<256, threads, 0, stream>>>(sortedPts, cellStart, qn, queue, knn);
    crf_iter_kernel<<<cblocks, threads, 0, stream>>>(ls, W, knn, q0s, q1s, orig,
                                                     nullptr, nullptr);
    crf_iter_kernel<<<cblocks, threads, 0, stream>>>(ls, W, knn, q1s, q0s, orig,
                                                     nullptr, nullptr);
    crf_iter_kernel<<<cblocks, threads, 0, stream>>>(ls, W, knn, q0s, nullptr, orig,
                                                     out, out + N_PTS * NCLS);
}

// Round 5
// 126.406 us; speedup vs baseline: 1.5571x; 1.1820x over previous
//
#include <hip/hip_runtime.h>

#define N_PTS 20000
#define NCLS 20
#define KNN 16
#define GRID 12
#define NCELLS (GRID * GRID * GRID)
#define HCELL (1.0f / (float)GRID)
#define CAND_CAP 640       // worst staged block: bd>=2 hs=2 clipped 5^3 E~521 +5sig
#define KEY_CAP 128        // filtered keys per point (E~26; taumax corner E~48, edge E~96)
#define R_TARGET 0.0680f   // radius giving E[cnt]~26 in the interior

__device__ __forceinline__ int cell1d(float v) {
    int c = (int)(v * (float)GRID);
    return min(max(c, 0), GRID - 1);
}

// ---------------------------------------------------------------------------
// Count (grid-wide atomics) + fused scan: last block performs the 1728-cell
// exclusive scan. NO __threadfence: __syncthreads drains vmcnt, so every
// block's cellCount RMWs are at the coherence point before its doneCtr RMW;
// the last block's agent-scope loads therefore see all counts (validated
// fence-free in round 2). Non-last blocks return immediately (no spin).
// ---------------------------------------------------------------------------
__global__ __launch_bounds__(256) void count_scan_kernel(const float* __restrict__ coords,
                                                         int* __restrict__ cellCount,
                                                         int* __restrict__ doneCtr,
                                                         int* __restrict__ cellStart,
                                                         int* __restrict__ cellCursor) {
    const int p = blockIdx.x * blockDim.x + threadIdx.x;
    if (p < N_PTS) {
        const int cx = cell1d(coords[3 * p + 0]);
        const int cy = cell1d(coords[3 * p + 1]);
        const int cz = cell1d(coords[3 * p + 2]);
        atomicAdd(&cellCount[(cz * GRID + cy) * GRID + cx], 1);
    }
    __syncthreads();                          // vmcnt(0): count RMWs retired
    __shared__ bool isLast;
    if (threadIdx.x == 0)
        isLast = (atomicAdd(doneCtr, 1) == (int)gridDim.x - 1);
    __syncthreads();
    if (!isLast) return;

    __shared__ int part[256];
    const int t = threadIdx.x;
    const int base = t * 7;                   // 256*7 = 1792 >= 1728
    int local[7];
    int s = 0;
#pragma unroll
    for (int i = 0; i < 7; ++i) {
        const int c = base + i;
        const int v = (c < NCELLS)
            ? __hip_atomic_load(&cellCount[c], __ATOMIC_RELAXED, __HIP_MEMORY_SCOPE_AGENT)
            : 0;
        local[i] = s;
        s += v;
    }
    part[t] = s;
    __syncthreads();
    for (int off = 1; off < 256; off <<= 1) {
        const int v = part[t] + ((t >= off) ? part[t - off] : 0);
        __syncthreads();
        part[t] = v;
        __syncthreads();
    }
    const int excl = (t > 0) ? part[t - 1] : 0;
#pragma unroll
    for (int i = 0; i < 7; ++i) {
        const int c = base + i;
        if (c < NCELLS) {
            cellStart[c] = excl + local[i];
            cellCursor[c] = excl + local[i];
        }
    }
    if (t == 255) cellStart[NCELLS] = part[255];
}

// ---------------------------------------------------------------------------
// Scatter (counting sort) + gather logits row + FUSED softmax -> q0s, ls.
// Round-0 proven.
// ---------------------------------------------------------------------------
__global__ __launch_bounds__(256) void scatter_kernel(const float* __restrict__ coords,
                                                      const float* __restrict__ logits,
                                                      int* __restrict__ cellCursor,
                                                      float4* __restrict__ sortedPts,
                                                      int* __restrict__ orig,
                                                      float* __restrict__ ls,
                                                      float* __restrict__ q0s) {
    const int p = blockIdx.x * blockDim.x + threadIdx.x;
    if (p >= N_PTS) return;
    const float x = coords[3 * p + 0];
    const float y = coords[3 * p + 1];
    const float z = coords[3 * p + 2];
    const int c = (cell1d(z) * GRID + cell1d(y)) * GRID + cell1d(x);
    const int pos = atomicAdd(&cellCursor[c], 1);
    sortedPts[pos] = make_float4(x, y, z, __uint_as_float((unsigned)p));
    orig[pos] = p;
    const float4* l4 = (const float4*)(logits + p * NCLS);
    float v[NCLS];
#pragma unroll
    for (int u = 0; u < 5; ++u) {
        const float4 a = l4[u];
        v[4 * u + 0] = a.x; v[4 * u + 1] = a.y;
        v[4 * u + 2] = a.z; v[4 * u + 3] = a.w;
    }
    float4* d4 = (float4*)(ls + pos * NCLS);
#pragma unroll
    for (int u = 0; u < 5; ++u)
        d4[u] = make_float4(v[4 * u], v[4 * u + 1], v[4 * u + 2], v[4 * u + 3]);
    float mx = v[0];
#pragma unroll
    for (int cc = 1; cc < NCLS; ++cc) mx = fmaxf(mx, v[cc]);
    float sum = 0.f;
#pragma unroll
    for (int cc = 0; cc < NCLS; ++cc) { v[cc] = __expf(v[cc] - mx); sum += v[cc]; }
    const float inv = 1.f / sum;
    float4* q4 = (float4*)(q0s + pos * NCLS);
#pragma unroll
    for (int u = 0; u < 5; ++u)
        q4[u] = make_float4(v[4 * u] * inv, v[4 * u + 1] * inv,
                            v[4 * u + 2] * inv, v[4 * u + 3] * inv);
}

// ---------------------------------------------------------------------------
// Rare exact fallback: wave-cooperative global-memory ladder (hw growing).
// Inline again (round-4 data: queue+separate dispatch was +20us vs inline on
// the sorted layout -- inline ladders were never the tail here).
// ---------------------------------------------------------------------------
__device__ void knn_ladder(const float4* __restrict__ sortedPts,
                           const int* __restrict__ cellStart,
                           const float4 qp, const int s, int hw,
                           unsigned long long* keys, const int lane,
                           int* __restrict__ knn_out) {
    const unsigned long long laneLt = (1ull << lane) - 1ull;
    const int cx = cell1d(qp.x), cy = cell1d(qp.y), cz = cell1d(qp.z);
    float g = 0.9995f * (float)hw * HCELL;
    float tau = g * g;
    int cnt = 0;
    for (int att = 0; att < 16; ++att) {
        cnt = 0;
        const int xlo = max(cx - hw, 0), xhi = min(cx + hw, GRID - 1);
        const int ylo = max(cy - hw, 0), yhi = min(cy + hw, GRID - 1);
        const int zlo = max(cz - hw, 0), zhi = min(cz + hw, GRID - 1);
        for (int zz = zlo; zz <= zhi; ++zz) {
            for (int yy = ylo; yy <= yhi; ++yy) {
                const int rowc = (zz * GRID + yy) * GRID;
                const int beg = cellStart[rowc + xlo];
                const int end = cellStart[rowc + xhi + 1];
                for (int j0 = beg; j0 < end; j0 += 64) {
                    const int j = j0 + lane;
                    const bool jv = j < end;
                    const float4 pt = sortedPts[jv ? j : beg];
                    const float dx = pt.x - qp.x, dy = pt.y - qp.y, dz = pt.z - qp.z;
                    const float d2 = dx * dx + dy * dy + dz * dz;
                    const bool take = jv && (d2 < tau);
                    const unsigned long long mm = __ballot(take);
                    if (take) {
                        const int pos = cnt + (int)__popcll(mm & laneLt);
                        if (pos < KEY_CAP)
                            keys[pos] = (((unsigned long long)__float_as_uint(d2)) << 32) |
                                        (unsigned long long)(unsigned)j;
                    }
                    cnt += (int)__popcll(mm);
                }
            }
        }
        if (cnt >= KNN && cnt <= KEY_CAP) break;
        if (cnt < KNN) {
            if (hw < GRID - 1) { ++hw; g = 0.9995f * (float)hw * HCELL; tau = g * g; }
            else tau *= 2.5f;
        } else {
            tau *= 0.6f;
        }
    }
    const int m = min(cnt, KEY_CAP);
    const unsigned long long k0 = (lane < m) ? keys[lane] : ~0ull;
    const unsigned long long k1 = (lane + 64 < m) ? keys[lane + 64] : ~0ull;
    int r0 = 0, r1 = 0;
    for (int j = 0; j < m; ++j) {
        const unsigned long long kj = keys[j];
        r0 += (kj < k0); r1 += (kj < k1);
    }
    if (lane < m && r0 < KNN)      knn_out[s * KNN + r0] = (int)(unsigned)(k0 & 0xffffffffull);
    if (lane + 64 < m && r1 < KNN) knn_out[s * KNN + r1] = (int)(unsigned)(k1 & 0xffffffffull);
}

// ---------------------------------------------------------------------------
// kNN: ONE block per cell (1728 blocks, 14.3KB LDS, 8 blocks/CU -> the WHOLE
// grid is co-resident in a single batch; 2048 block slots machine-wide).
// vs round-0's 2 blocks/cell: halves the duplicated halo staging, cellStart
// row reads, and prefix-scan prologue. 4 waves stride the cell's points.
// ---------------------------------------------------------------------------
__global__ __launch_bounds__(256) void knn_kernel(const float4* __restrict__ sortedPts,
                                                  const int* __restrict__ cellStart,
                                                  int* __restrict__ knn_out) {
    __shared__ float4 cand[CAND_CAP];                 // 10.24 KB
    __shared__ unsigned long long keys[4][KEY_CAP];   // 4 KB
    const int lane = threadIdx.x & 63;
    const int wave = threadIdx.x >> 6;
    const int c = blockIdx.x;
    const int cz = c / (GRID * GRID);
    const int cy = (c / GRID) % GRID;
    const int cx = c % GRID;
    const int pbeg = cellStart[c];
    const int pend = cellStart[c + 1];
    const int npts = pend - pbeg;
    if (npts <= 0) return;
    const int bd = (cx == 0 || cx == GRID - 1) + (cy == 0 || cy == GRID - 1) +
                   (cz == 0 || cz == GRID - 1);
    const int hs = (bd >= 2) ? 2 : 1;                 // staging halo width
    const unsigned long long laneLt = (1ull << lane) - 1ull;

    const int xlo = max(cx - hs, 0), xhi = min(cx + hs, GRID - 1);
    const int ylo = max(cy - hs, 0), yhi = min(cy + hs, GRID - 1);
    const int zlo = max(cz - hs, 0), zhi = min(cz + hs, GRID - 1);
    const int ny = yhi - ylo + 1;
    const int nruns = (zhi - zlo + 1) * ny;           // <= 25 x-contiguous runs

    int beg = 0, len = 0;
    if (lane < nruns) {
        const int zz = zlo + lane / ny;
        const int yy = ylo + lane % ny;
        const int rowc = (zz * GRID + yy) * GRID;
        beg = cellStart[rowc + xlo];
        len = cellStart[rowc + xhi + 1] - beg;
    }
    int off = len;
#pragma unroll
    for (int sh = 1; sh < 32; sh <<= 1) {
        const int o = __shfl_up(off, sh, 64);
        if (lane >= sh) off += o;
    }
    const int nc = __shfl(off, nruns - 1);
    off -= len;                                        // exclusive
    const int ownRun = (cz - zlo) * ny + (cy - ylo);
    const int ownOff = __shfl(off, ownRun) + (pbeg - __shfl(beg, ownRun));

    if (nc <= CAND_CAP) {
        for (int r = wave; r < nruns; r += 4) {
            const int rb = __shfl(beg, r);
            const int rl = __shfl(len, r);
            const int ro = __shfl(off, r);
            for (int i = lane; i < rl; i += 64) {
                float4 pt = sortedPts[rb + i];
                pt.w = __uint_as_float((unsigned)(rb + i));
                cand[ro + i] = pt;
            }
        }
    }
    __syncthreads();

    if (nc > CAND_CAP) {                               // ~never (>5 sigma)
        for (int idx = wave; idx < npts; idx += 4)
            knn_ladder(sortedPts, cellStart, sortedPts[pbeg + idx], pbeg + idx,
                       hs, keys[wave], lane, knn_out);
        return;
    }

    const float taumaxr = 0.9995f * (float)hs * HCELL;
    const float taumax = taumaxr * taumaxr;

    for (int idx = wave; idx < npts; idx += 4) {
        const int s = pbeg + idx;
        const float4 qp = cand[ownOff + idx];
        // boundary-corrected tau targeting E[cnt]~26, capped at coverage hs*h
        float r = R_TARGET;
        const float inv2r = 0.5f / r;
        const float fx = (fminf(qp.x + r, 1.f) - fmaxf(qp.x - r, 0.f)) * inv2r;
        const float fy = (fminf(qp.y + r, 1.f) - fmaxf(qp.y - r, 0.f)) * inv2r;
        const float fz = (fminf(qp.z + r, 1.f) - fmaxf(qp.z - r, 0.f)) * inv2r;
        const float f = fmaxf(fx * fy * fz, 0.05f);
        r = R_TARGET * __powf(f, -0.33333334f);
        float tau = fminf(r * r, taumax);
        bool triedMax = (tau >= taumax * 0.999f);

        int cnt = 0;
        bool ok = false;
        for (int att = 0; att < 5 && !ok; ++att) {
            cnt = 0;
            for (int j0 = 0; j0 < nc; j0 += 64) {
                const int j = j0 + lane;
                float d2 = 1e30f;
                unsigned pw = 0;
                if (j < nc) {
                    const float4 pt = cand[j];
                    const float dx = pt.x - qp.x, dy = pt.y - qp.y, dz = pt.z - qp.z;
                    d2 = dx * dx + dy * dy + dz * dz;
                    pw = __float_as_uint(pt.w);
                }
                const bool take = d2 < tau;
                const unsigned long long mm = __ballot(take);
                if (take) {
                    const int pos = cnt + (int)__popcll(mm & laneLt);
                    if (pos < KEY_CAP)
                        keys[wave][pos] =
                            (((unsigned long long)__float_as_uint(d2)) << 32) |
                            (unsigned long long)pw;
                }
                cnt += (int)__popcll(mm);
            }
            if (cnt >= KNN && cnt <= KEY_CAP) ok = true;
            else if (cnt < KNN) {
                if (triedMax) break;                   // needs radius > hs*h -> ladder
                tau = taumax; triedMax = true;
            } else tau *= 0.6f;
        }
        if (!ok) {                                     // rare Poisson-tail points
            knn_ladder(sortedPts, cellStart, qp, s, hs + 1, keys[wave], lane, knn_out);
            continue;
        }
        const int m = cnt;
        const unsigned long long k0 = (lane < m) ? keys[wave][lane] : ~0ull;
        const unsigned long long k1 = (lane + 64 < m) ? keys[wave][lane + 64] : ~0ull;
        int r0 = 0, r1 = 0;
        for (int j = 0; j < m; ++j) {
            const unsigned long long kj = keys[wave][j];   // LDS broadcast
            r0 += (kj < k0); r1 += (kj < k1);
        }
        if (lane < m && r0 < KNN)      knn_out[s * KNN + r0] = (int)(unsigned)(k0 & 0xffffffffull);
        if (lane + 64 < m && r1 < KNN) knn_out[s * KNN + r1] = (int)(unsigned)(k1 & 0xffffffffull);
    }
}

// ---------------------------------------------------------------------------
// CRF iteration, SORTED space, 4 lanes/point. Round-0 proven.
// ---------------------------------------------------------------------------
__global__ __launch_bounds__(256) void crf_iter_kernel(const float* __restrict__ ls,
                                                       const float* __restrict__ W,
                                                       const int* __restrict__ knn,
                                                       const float* __restrict__ qin,
                                                       float* __restrict__ qout,
                                                       const int* __restrict__ orig,
                                                       float* __restrict__ outRef,
                                                       float* __restrict__ outQ) {
    __shared__ float Ws[NCLS * NCLS];
    for (int i = threadIdx.x; i < NCLS * NCLS; i += blockDim.x) Ws[i] = W[i];
    __syncthreads();
    const int t = blockIdx.x * blockDim.x + threadIdx.x;
    const int p = t >> 2;
    const int qtr = t & 3;
    if (p >= N_PTS) return;

    float acc[NCLS];
#pragma unroll
    for (int c = 0; c < NCLS; ++c) acc[c] = 0.f;

    const int4 k4 = ((const int4*)(knn + p * KNN))[qtr];
    const int ids[4] = {k4.x, k4.y, k4.z, k4.w};
#pragma unroll
    for (int u = 0; u < 4; ++u) {
        unsigned id = (unsigned)ids[u];
        if (id >= N_PTS) id = 0;        // safety clamp (unreachable)
        const float4* r4 = (const float4*)(qin + id * NCLS);
#pragma unroll
        for (int v = 0; v < 5; ++v) {
            const float4 a = r4[v];
            acc[4 * v + 0] += a.x; acc[4 * v + 1] += a.y;
            acc[4 * v + 2] += a.z; acc[4 * v + 3] += a.w;
        }
    }
#pragma unroll
    for (int c = 0; c < NCLS; ++c) {
        acc[c] += __shfl_xor(acc[c], 1, 64);
        acc[c] += __shfl_xor(acc[c], 2, 64);
        acc[c] *= (1.f / 16.f);          // msg
    }

    const int c0 = qtr * 5;
    float ref[5];
#pragma unroll
    for (int i = 0; i < 5; ++i) {
        float s = ls[p * NCLS + c0 + i];
#pragma unroll
        for (int k = 0; k < NCLS; ++k) s += acc[k] * Ws[(c0 + i) * NCLS + k];  // x@W^T
        ref[i] = s;
    }

    float mx = ref[0];
#pragma unroll
    for (int i = 1; i < 5; ++i) mx = fmaxf(mx, ref[i]);
    mx = fmaxf(mx, __shfl_xor(mx, 1, 64));
    mx = fmaxf(mx, __shfl_xor(mx, 2, 64));
    float ex[5];
    float ps = 0.f;
#pragma unroll
    for (int i = 0; i < 5; ++i) { ex[i] = __expf(ref[i] - mx); ps += ex[i]; }
    ps += __shfl_xor(ps, 1, 64);
    ps += __shfl_xor(ps, 2, 64);
    const float inv = 1.f / ps;

    if (outRef != nullptr) {
        const int o = orig[p];
#pragma unroll
        for (int i = 0; i < 5; ++i) {
            outRef[o * NCLS + c0 + i] = ref[i];
            outQ[o * NCLS + c0 + i] = ex[i] * inv;
        }
    } else {
#pragma unroll
        for (int i = 0; i < 5; ++i) qout[p * NCLS + c0 + i] = ex[i] * inv;
    }
}

// ---------------------------------------------------------------------------
extern "C" void kernel_launch(void* const* d_in, const int* in_sizes, int n_in,
                              void* d_out, int out_size, void* d_ws, size_t ws_size,
                              hipStream_t stream) {
    const float* logits = (const float*)d_in[0];   // (20000, 20)
    const float* coords = (const float*)d_in[1];   // (20000, 3)
    const float* W      = (const float*)d_in[2];   // (20, 20)
    float* out = (float*)d_out;                    // refined (400000) | q (400000)

    // workspace (~5 MB); q1s aliases out's q-region (safe: final pass reads
    // only q0s/ls/knn/orig and overwrites that region last).
    char* ws = (char*)d_ws;
    size_t off = 0;
    int* knn = (int*)(ws + off);              off += (size_t)N_PTS * KNN * 4;
    off = (off + 255) & ~(size_t)255;
    float* ls = (float*)(ws + off);           off += (size_t)N_PTS * NCLS * 4;
    off = (off + 255) & ~(size_t)255;
    float* q0s = (float*)(ws + off);          off += (size_t)N_PTS * NCLS * 4;
    off = (off + 255) & ~(size_t)255;
    float4* sortedPts = (float4*)(ws + off);  off += (size_t)N_PTS * 16;
    off = (off + 255) & ~(size_t)255;
    int* orig = (int*)(ws + off);             off += (size_t)N_PTS * 4;
    off = (off + 255) & ~(size_t)255;
    int* cellCount = (int*)(ws + off);        off += (size_t)(NCELLS + 1) * 4;
    int* doneCtr   = cellCount + NCELLS;      // zeroed with cellCount
    off = (off + 255) & ~(size_t)255;
    int* cellStart = (int*)(ws + off);        off += (size_t)(NCELLS + 1) * 4;
    off = (off + 255) & ~(size_t)255;
    int* cellCursor = (int*)(ws + off);
    float* q1s = out + N_PTS * NCLS;

    const int threads = 256;
    const int pblocks = (N_PTS + threads - 1) / threads;      // 79
    const int cblocks = (4 * N_PTS + threads - 1) / threads;  // 313

    hipMemsetAsync(cellCount, 0, (NCELLS + 1) * sizeof(int), stream);
    count_scan_kernel<<<pblocks, threads, 0, stream>>>(coords, cellCount, doneCtr,
                                                       cellStart, cellCursor);
    scatter_kernel<<<pblocks, threads, 0, stream>>>(coords, logits, cellCursor,
                                                    sortedPts, orig, ls, q0s);
    knn_kernel<<<NCELLS, threads, 0, stream>>>(sortedPts, cellStart, knn);
    crf_iter_kernel<<<cblocks, threads, 0, stream>>>(ls, W, knn, q0s, q1s, orig,
                                                     nullptr, nullptr);
    crf_iter_kernel<<<cblocks, threads, 0, stream>>>(ls, W, knn, q1s, q0s, orig,
                                                     nullptr, nullptr);
    crf_iter_kernel<<<cblocks, threads, 0, stream>>>(ls, W, knn, q0s, nullptr, orig,
                                                     out, out + N_PTS * NCLS);
}